// Round 1
// 1302.919 us; speedup vs baseline: 1.3927x; 1.3927x over previous
//
#include <hip/hip_runtime.h>
#include <hip/hip_bf16.h>
#include <math.h>

#define NTOK   4096   // B*T
#define TSEQ   2048
#define DMODEL 1024
#define DINNER 2048
#define NSTATE 16
#define DTRANK 64
#define NEXP   8
#define DFF    2048
#define NCHUNK 16
#define CLEN   128    // TSEQ / NCHUNK

typedef __attribute__((ext_vector_type(8))) short short8;
typedef __attribute__((ext_vector_type(4))) float f32x4;

__device__ __forceinline__ float siluf(float x){ return x / (1.f + expf(-x)); }

// fp32 -> bf16 (round-to-nearest-even), as raw ushort
__device__ __forceinline__ unsigned short f2bf(float x){
  unsigned int u = __float_as_uint(x);
  unsigned int r = (u + 0x7FFFu + ((u >> 16) & 1u)) >> 16;
  return (unsigned short)r;
}

// split fp32 -> (hi, lo) bf16 pair: x ~= hi + lo, |err| <= 2^-18 |x|
__device__ __forceinline__ void split4(float4 a, unsigned short* hi, unsigned short* lo){
  float av[4] = {a.x, a.y, a.z, a.w};
  #pragma unroll
  for (int j=0;j<4;j++){
    unsigned short hu = f2bf(av[j]);
    float hf = __uint_as_float((unsigned int)hu << 16);
    hi[j] = hu;
    lo[j] = f2bf(av[j] - hf);
  }
}

// ---------------------------------------------------------------------------
// zero counters (cnt/fill/off = 64 ints)
// ---------------------------------------------------------------------------
__global__ void zero_kernel(int* __restrict__ p){ p[threadIdx.x] = 0; }

// ---------------------------------------------------------------------------
// Pre-split an fp32 array into hi/lo bf16 arrays. n multiple of 1024.
// ---------------------------------------------------------------------------
__global__ __launch_bounds__(256) void split_kernel(
    const float* __restrict__ in, unsigned short* __restrict__ hi,
    unsigned short* __restrict__ lo, int n)
{
  int i = (blockIdx.x*256 + threadIdx.x)*4;
  if (i >= n) return;
  float4 v = *(const float4*)(in + i);
  unsigned short ht[4], lt[4];
  split4(v, ht, lt);
  uint2 hw, lw;
  hw.x = (unsigned)ht[0] | ((unsigned)ht[1]<<16);
  hw.y = (unsigned)ht[2] | ((unsigned)ht[3]<<16);
  lw.x = (unsigned)lt[0] | ((unsigned)lt[1]<<16);
  lw.y = (unsigned)lt[2] | ((unsigned)lt[3]<<16);
  *(uint2*)(hi+i) = hw;
  *(uint2*)(lo+i) = lw;
}

// ---------------------------------------------------------------------------
// Split-bf16 MFMA GEMM: C[M,N] = A[M,K] @ W[N,K]^T (+epilogue), ~fp32 accuracy.
// A is fp32 (split to hi/lo in-kernel); W is pre-split (Whi/Wlo bf16 ushort).
// Per product: ah*bh + al*bh + ah*bl (drop al*bl, <=2^-18 rel) in fp32 acc.
// Tile BM x 64, BK=32, 256 threads / 4 waves; wave owns BM/4 rows x 64 cols.
// mfma_f32_16x16x32_bf16: A[m=lane&15][k=quad*8+j]; D: col=lane&15,row=quad*4+r.
// LDS row stride 40 shorts (80B, 16B-aligned b128, <=2-way banks; moe_gemm-proven).
// EPI: 0 = +bias | 1 = plain | 2 = +bias,softplus | 3 = +resid
// M must be a multiple of BM (always 4096 here); N,K arbitrary mult. of 32 on K.
// ---------------------------------------------------------------------------
template<int EPI, int BM>
__global__ __launch_bounds__(256) void gemm_mfma(
    const float* __restrict__ A, int lda,
    const unsigned short* __restrict__ Whi, const unsigned short* __restrict__ Wlo, int ldw,
    int M, int N, int K,
    const float* __restrict__ bias,
    const float* __restrict__ resid, int ldr,
    float* __restrict__ out, int ldo)
{
  constexpr int TA = BM/8;      // fp32 A elems staged per thread (16 or 8)
  constexpr int RG = BM/64;     // 16-row groups per wave (2 or 1)
  const int tid = threadIdx.x;
  const int m0 = blockIdx.y * BM;
  const int n0 = blockIdx.x * 64;

  __shared__ __align__(16) unsigned short Ahs[BM*40];
  __shared__ __align__(16) unsigned short Als[BM*40];
  __shared__ __align__(16) unsigned short Whs[64*40];
  __shared__ __align__(16) unsigned short Wls[64*40];

  // staging indices: A: (32/TA) threads per row; W: 4 threads per row (8 shorts each)
  const int arow = tid / (32/TA);
  const int ak   = (tid % (32/TA)) * TA;
  const int wrow = tid >> 2;
  const int wk   = (tid & 3) * 8;

  const float* Ap = A + (size_t)(m0 + arow)*lda + ak;
  const bool wok = (n0 + wrow) < N;
  const unsigned short* Whp = Whi + (size_t)(n0 + wrow)*ldw + wk;
  const unsigned short* Wlp = Wlo + (size_t)(n0 + wrow)*ldw + wk;

  const int lane = tid & 63;
  const int wv   = tid >> 6;
  const int qd   = lane >> 4;
  const int mr   = lane & 15;

  f32x4 acc[RG][4];
  #pragma unroll
  for (int rg=0; rg<RG; rg++)
    #pragma unroll
    for (int ct=0; ct<4; ct++) acc[rg][ct] = (f32x4){0.f,0.f,0.f,0.f};

  const unsigned short* ardh = &Ahs[(wv*(16*RG) + mr)*40 + qd*8];
  const unsigned short* ardl = &Als[(wv*(16*RG) + mr)*40 + qd*8];
  const unsigned short* brdh = &Whs[mr*40 + qd*8];
  const unsigned short* brdl = &Wls[mr*40 + qd*8];

  const short8 z8 = {0,0,0,0,0,0,0,0};

  for (int kt = 0; kt < K; kt += 32){
    // load + split A (fp32 -> hi/lo bf16)
    short8 ahi[TA/8], alo[TA/8];
    #pragma unroll
    for (int h=0; h<TA/8; h++){
      unsigned short ht[8], lt[8];
      split4(*(const float4*)(Ap + kt + h*8),     ht,   lt);
      split4(*(const float4*)(Ap + kt + h*8 + 4), ht+4, lt+4);
      #pragma unroll
      for (int j=0;j<8;j++){ ahi[h][j]=(short)ht[j]; alo[h][j]=(short)lt[j]; }
    }
    short8 wh8 = wok ? *(const short8*)(Whp + kt) : z8;
    short8 wl8 = wok ? *(const short8*)(Wlp + kt) : z8;
    __syncthreads();
    #pragma unroll
    for (int h=0; h<TA/8; h++){
      *(short8*)&Ahs[arow*40 + ak + h*8] = ahi[h];
      *(short8*)&Als[arow*40 + ak + h*8] = alo[h];
    }
    *(short8*)&Whs[wrow*40 + wk] = wh8;
    *(short8*)&Wls[wrow*40 + wk] = wl8;
    __syncthreads();
    #pragma unroll
    for (int rg=0; rg<RG; rg++){
      short8 ah = *(const short8*)(ardh + rg*16*40);
      short8 al = *(const short8*)(ardl + rg*16*40);
      #pragma unroll
      for (int ct=0; ct<4; ct++){
        short8 bh = *(const short8*)(brdh + ct*16*40);
        short8 bl = *(const short8*)(brdl + ct*16*40);
        f32x4 t = acc[rg][ct];
        t = __builtin_amdgcn_mfma_f32_16x16x32_bf16(ah, bh, t, 0,0,0);
        t = __builtin_amdgcn_mfma_f32_16x16x32_bf16(al, bh, t, 0,0,0);
        t = __builtin_amdgcn_mfma_f32_16x16x32_bf16(ah, bl, t, 0,0,0);
        acc[rg][ct] = t;
      }
    }
  }

  #pragma unroll
  for (int rg=0; rg<RG; rg++){
    #pragma unroll
    for (int ct=0; ct<4; ct++){
      int colg = n0 + ct*16 + mr;
      if (colg >= N) continue;
      float bias_v = (EPI==0 || EPI==2) ? bias[colg] : 0.f;
      #pragma unroll
      for (int r=0;r<4;r++){
        int rowg = m0 + wv*(16*RG) + rg*16 + qd*4 + r;
        float v = acc[rg][ct][r];
        if (EPI == 0){ v += bias_v; }
        else if (EPI == 2){ v += bias_v; v = (v > 20.f) ? v : log1pf(expf(v)); }
        else if (EPI == 3){ v += resid[(size_t)rowg*ldr + colg]; }
        out[(size_t)rowg*ldo + colg] = v;
      }
    }
  }
}

// ---------------------------------------------------------------------------
// LayerNorm over D=1024, one token per 256-thread block (all fp32)
// ---------------------------------------------------------------------------
__global__ __launch_bounds__(256) void ln_kernel(
    const float* __restrict__ x, const float* __restrict__ g, const float* __restrict__ b,
    float* __restrict__ out)
{
  int tok = blockIdx.x;
  int tid = threadIdx.x;
  const float* row = x + (size_t)tok * DMODEL;
  float v[4];
  float s = 0.f, sq = 0.f;
  #pragma unroll
  for (int j=0;j<4;j++){
    v[j] = row[j*256 + tid];
    s += v[j]; sq += v[j]*v[j];
  }
  #pragma unroll
  for (int o=1;o<64;o<<=1){ s += __shfl_xor(s,o,64); sq += __shfl_xor(sq,o,64); }
  __shared__ float ss[4], ssq[4];
  int wid = tid >> 6, lane = tid & 63;
  if (lane == 0){ ss[wid]=s; ssq[wid]=sq; }
  __syncthreads();
  s  = ss[0]+ss[1]+ss[2]+ss[3];
  sq = ssq[0]+ssq[1]+ssq[2]+ssq[3];
  float mu = s * (1.f/DMODEL);
  float var = sq * (1.f/DMODEL) - mu*mu;
  float rs = rsqrtf(var + 1e-5f);
  #pragma unroll
  for (int j=0;j<4;j++){
    int d = j*256 + tid;
    out[(size_t)tok*DMODEL + d] = (v[j]-mu)*rs*g[d] + b[d];
  }
}

// ---------------------------------------------------------------------------
// Causal depthwise conv (KC=4) + SiLU.  xi = xz[:, 0:2048] (row stride 4096)
// ---------------------------------------------------------------------------
__global__ __launch_bounds__(256) void conv_kernel(
    const float* __restrict__ xz, const float* __restrict__ cw,
    const float* __restrict__ cb, float* __restrict__ xc)
{
  int i = blockIdx.x*256 + threadIdx.x;      // < NTOK*DINNER
  int tok = i >> 11;
  int ch  = i & 2047;
  int t   = tok & (TSEQ-1);
  int b   = tok >> 11;
  float acc = cb[ch];
  #pragma unroll
  for (int k=0;k<4;k++){
    int tt = t + k - 3;
    if (tt >= 0)
      acc = fmaf(cw[ch*4 + k], xz[(size_t)((b<<11)+tt)*4096 + ch], acc);
  }
  xc[i] = siluf(acc);
}

// ---------------------------------------------------------------------------
// Chunked parallel selective scan (3 passes), verified.
// ---------------------------------------------------------------------------
__global__ __launch_bounds__(256) void scan_partial(
    const float* __restrict__ xz, const float* __restrict__ xc,
    const float* __restrict__ proj, const float* __restrict__ A_log,
    float* __restrict__ P, float* __restrict__ Q)
{
  int tid = threadIdx.x;
  int n = tid & 15, chi = tid >> 4;
  int ch = blockIdx.x*16 + chi;
  int c  = blockIdx.y;
  int b  = blockIdx.z;
  float A = -expf(A_log[ch*NSTATE + n]);
  float h = 0.f, sdt = 0.f;
  int tok0 = (b<<11) + c*CLEN;
  for (int i=0;i<CLEN;i++){
    int tok = tok0 + i;
    float dtv = xz[(size_t)tok*4096 + ch];
    float xt  = xc[(size_t)tok*2048 + ch];
    float Bn  = proj[(size_t)tok*96 + 64 + n];
    h = expf(dtv*A)*h + dtv*xt*Bn;
    sdt += dtv;
  }
  size_t idx = ((((size_t)(b*NCHUNK + c))<<11 | ch)<<4) | n;
  P[idx] = expf(A*sdt);
  Q[idx] = h;
}

__global__ __launch_bounds__(256) void scan_combine(
    const float* __restrict__ P, const float* __restrict__ Q,
    float* __restrict__ Hs)
{
  int g = blockIdx.x*256 + threadIdx.x;   // 65536 = b*32768 + ch*16 + n
  int n = g & 15, ch = (g>>4) & 2047, b = g>>15;
  float hs = 0.f;
  for (int c=0;c<NCHUNK;c++){
    size_t idx = ((((size_t)(b*NCHUNK + c))<<11 | ch)<<4) | n;
    Hs[idx] = hs;
    hs = fmaf(P[idx], hs, Q[idx]);
  }
}

__global__ __launch_bounds__(256) void scan_final(
    const float* __restrict__ xz, float* __restrict__ xc,
    const float* __restrict__ proj, const float* __restrict__ A_log,
    const float* __restrict__ Dskip, const float* __restrict__ Hs)
{
  int tid = threadIdx.x;
  int n = tid & 15, chi = tid >> 4;
  int ch = blockIdx.x*16 + chi;
  int c  = blockIdx.y;
  int b  = blockIdx.z;
  float A  = -expf(A_log[ch*NSTATE + n]);
  float Dv = Dskip[ch];
  size_t idx = ((((size_t)(b*NCHUNK + c))<<11 | ch)<<4) | n;
  float h = Hs[idx];
  int tok0 = (b<<11) + c*CLEN;
  for (int i=0;i<CLEN;i++){
    int tok = tok0 + i;
    float dtv = xz[(size_t)tok*4096 + ch];
    float xt  = xc[(size_t)tok*2048 + ch];
    float Bn  = proj[(size_t)tok*96 + 64 + n];
    float Cn  = proj[(size_t)tok*96 + 80 + n];
    h = expf(dtv*A)*h + dtv*xt*Bn;
    float p = h*Cn;
    p += __shfl_xor(p,1,64);
    p += __shfl_xor(p,2,64);
    p += __shfl_xor(p,4,64);
    p += __shfl_xor(p,8,64);
    if (n == 0){
      float zv = xz[(size_t)tok*4096 + 2048 + ch];
      xc[(size_t)tok*2048 + ch] = (p + xt*Dv) * siluf(zv);
    }
  }
}

// ---------------------------------------------------------------------------
// Router: logits, softmax (-> d_out probs), top-2, atomic expert counts
// ---------------------------------------------------------------------------
__global__ __launch_bounds__(256) void router_kernel(
    const float* __restrict__ hmoe, const float* __restrict__ rw,
    float* __restrict__ probs_out, int* __restrict__ cnt,
    int* __restrict__ tok_e0, int* __restrict__ tok_e1,
    float* __restrict__ tok_w0, float* __restrict__ tok_w1)
{
  int tok = blockIdx.x;
  int tid = threadIdx.x;
  int e = tid >> 5, l = tid & 31;
  float s = 0.f;
  const float* row = hmoe + (size_t)tok*DMODEL;
  const float* wr  = rw + (size_t)e*DMODEL;
  for (int d=l; d<DMODEL; d+=32) s = fmaf(row[d], wr[d], s);
  #pragma unroll
  for (int o=1;o<32;o<<=1) s += __shfl_xor(s,o,64);
  __shared__ float lg[8];
  if (l==0) lg[e]=s;
  __syncthreads();
  if (tid==0){
    float mx = lg[0];
    for (int k=1;k<8;k++) mx = fmaxf(mx, lg[k]);
    float pe[8]; float den=0.f;
    for (int k=0;k<8;k++){ pe[k]=expf(lg[k]-mx); den+=pe[k]; }
    float inv = 1.f/den;
    for (int k=0;k<8;k++) probs_out[tok*8+k] = pe[k]*inv;
    int i0=0;
    for (int k=1;k<8;k++) if (pe[k] > pe[i0]) i0=k;
    int i1 = (i0==0)?1:0;
    for (int k=0;k<8;k++) if (k!=i0 && pe[k] > pe[i1]) i1=k;
    float v0=pe[i0], v1=pe[i1], sw=v0+v1;
    tok_e0[tok]=i0; tok_e1[tok]=i1;
    tok_w0[tok]=v0/sw; tok_w1[tok]=v1/sw;
    atomicAdd(&cnt[i0],1); atomicAdd(&cnt[i1],1);
  }
}

__global__ void prefix_kernel(const int* cnt, int* off, int* fill){
  if (threadIdx.x==0){
    int s=0;
    for (int e=0;e<NEXP;e++){ off[e]=s; s+=cnt[e]; fill[e]=0; }
  }
}

__global__ __launch_bounds__(256) void fill_kernel(
    const int* tok_e0, const int* tok_e1, const float* tok_w0, const float* tok_w1,
    const int* off, int* fill, int* slot_tok, float* slot_w)
{
  int tok = blockIdx.x*256 + threadIdx.x;
  int e0=tok_e0[tok], e1=tok_e1[tok];
  int p0 = atomicAdd(&fill[e0],1); int s0 = off[e0]+p0;
  slot_tok[s0]=tok; slot_w[s0]=tok_w0[tok];
  int p1 = atomicAdd(&fill[e1],1); int s1 = off[e1]+p1;
  slot_tok[s1]=tok; slot_w[s1]=tok_w1[tok];
}

// ---------------------------------------------------------------------------
// MoE GEMM1 via bf16 MFMA: H1[slot,DFF] = silu(hmoe[tok] @ w1[e]^T + b1[e])
// ---------------------------------------------------------------------------
__global__ __launch_bounds__(256) void moe_gemm1(
    const float* __restrict__ hmoe, const float* __restrict__ w1, const float* __restrict__ b1,
    const int* __restrict__ cnt, const int* __restrict__ off,
    const int* __restrict__ slot_tok, unsigned short* __restrict__ H1)
{
  int e = blockIdx.z;
  int c = cnt[e];
  int r0 = blockIdx.y*64;
  if (r0 >= c) return;
  int base = off[e];
  int tid = threadIdx.x;
  __shared__ int toks[64];
  if (tid < 64) toks[tid] = (r0 + tid < c) ? slot_tok[base + r0 + tid] : -1;
  __shared__ __align__(16) unsigned short As[64*40];
  __shared__ __align__(16) unsigned short Ws[64*40];
  __syncthreads();

  const int n0   = blockIdx.x*64;
  const int arow = tid >> 2;          // 0..63 staged row
  const int kq   = (tid & 3) * 8;     // k sub-offset 0/8/16/24
  const int tok  = toks[arow];
  const float* Ap = hmoe + (size_t)(tok < 0 ? 0 : tok)*DMODEL + kq;
  const bool aok  = (tok >= 0);
  const float* Wp = w1 + (size_t)e*DFF*DMODEL + (size_t)(n0+arow)*DMODEL + kq;

  const int lane = tid & 63;
  const int wv   = tid >> 6;
  const int qd   = lane >> 4;
  const int mr   = lane & 15;

  f32x4 acc0={0,0,0,0}, acc1={0,0,0,0}, acc2={0,0,0,0}, acc3={0,0,0,0};

  unsigned short* aw = &As[arow*40 + kq];
  unsigned short* ww = &Ws[arow*40 + kq];
  const unsigned short* ard = &As[(wv*16 + mr)*40 + qd*8];
  const unsigned short* brd = &Ws[mr*40 + qd*8];

  for (int kt = 0; kt < DMODEL; kt += 32){
    float4 a0 = aok ? *(const float4*)(Ap + kt)     : make_float4(0,0,0,0);
    float4 a1 = aok ? *(const float4*)(Ap + kt + 4) : make_float4(0,0,0,0);
    float4 w0 = *(const float4*)(Wp + kt);
    float4 w1v= *(const float4*)(Wp + kt + 4);
    short8 av, wvv;
    av[0]=(short)f2bf(a0.x); av[1]=(short)f2bf(a0.y); av[2]=(short)f2bf(a0.z); av[3]=(short)f2bf(a0.w);
    av[4]=(short)f2bf(a1.x); av[5]=(short)f2bf(a1.y); av[6]=(short)f2bf(a1.z); av[7]=(short)f2bf(a1.w);
    wvv[0]=(short)f2bf(w0.x); wvv[1]=(short)f2bf(w0.y); wvv[2]=(short)f2bf(w0.z); wvv[3]=(short)f2bf(w0.w);
    wvv[4]=(short)f2bf(w1v.x); wvv[5]=(short)f2bf(w1v.y); wvv[6]=(short)f2bf(w1v.z); wvv[7]=(short)f2bf(w1v.w);
    __syncthreads();
    *(short8*)aw = av;
    *(short8*)ww = wvv;
    __syncthreads();
    short8 af = *(const short8*)ard;
    short8 b0 = *(const short8*)(brd);
    short8 b1f= *(const short8*)(brd + 16*40);
    short8 b2f= *(const short8*)(brd + 32*40);
    short8 b3f= *(const short8*)(brd + 48*40);
    acc0 = __builtin_amdgcn_mfma_f32_16x16x32_bf16(af, b0, acc0, 0,0,0);
    acc1 = __builtin_amdgcn_mfma_f32_16x16x32_bf16(af, b1f, acc1, 0,0,0);
    acc2 = __builtin_amdgcn_mfma_f32_16x16x32_bf16(af, b2f, acc2, 0,0,0);
    acc3 = __builtin_amdgcn_mfma_f32_16x16x32_bf16(af, b3f, acc3, 0,0,0);
  }

  #pragma unroll
  for (int ct=0; ct<4; ct++){
    f32x4 a = (ct==0)?acc0:(ct==1)?acc1:(ct==2)?acc2:acc3;
    int colg = n0 + ct*16 + mr;
    float bias = b1[(size_t)e*DFF + colg];
    #pragma unroll
    for (int r=0;r<4;r++){
      int sl = wv*16 + qd*4 + r;
      if (toks[sl] < 0) continue;
      float v = a[r] + bias;
      H1[(size_t)(base + r0 + sl)*DFF + colg] = f2bf(siluf(v));
    }
  }
}

// ---------------------------------------------------------------------------
// MoE GEMM2 via bf16 MFMA: hres[tok] += w_slot*(H1[slot] @ w2[e]^T + b2[e])
// ---------------------------------------------------------------------------
__global__ __launch_bounds__(256) void moe_gemm2(
    const unsigned short* __restrict__ H1, const float* __restrict__ w2,
    const float* __restrict__ b2,
    const int* __restrict__ cnt, const int* __restrict__ off,
    const int* __restrict__ slot_tok, const float* __restrict__ slot_w,
    float* __restrict__ hres)
{
  int e = blockIdx.z;
  int c = cnt[e];
  int r0 = blockIdx.y*64;
  if (r0 >= c) return;
  int base = off[e];
  int tid = threadIdx.x;
  __shared__ int toks[64];
  __shared__ float wts[64];
  if (tid < 64){
    int r = r0 + tid;
    toks[tid] = (r<c) ? slot_tok[base+r] : -1;
    wts[tid]  = (r<c) ? slot_w[base+r] : 0.f;
  }
  __shared__ __align__(16) unsigned short As[64*40];
  __shared__ __align__(16) unsigned short Ws[64*40];
  __syncthreads();

  const int n0   = blockIdx.x*64;
  const int arow = tid >> 2;
  const int kq   = (tid & 3) * 8;
  const bool aok = (toks[arow] >= 0);
  const unsigned short* Ap = H1 + (size_t)(base + r0 + (aok ? arow : 0))*DFF + kq;
  const float* Wp = w2 + (size_t)e*DMODEL*DFF + (size_t)(n0+arow)*DFF + kq;

  const int lane = tid & 63;
  const int wv   = tid >> 6;
  const int qd   = lane >> 4;
  const int mr   = lane & 15;

  f32x4 acc0={0,0,0,0}, acc1={0,0,0,0}, acc2={0,0,0,0}, acc3={0,0,0,0};

  unsigned short* aw = &As[arow*40 + kq];
  unsigned short* ww = &Ws[arow*40 + kq];
  const unsigned short* ard = &As[(wv*16 + mr)*40 + qd*8];
  const unsigned short* brd = &Ws[mr*40 + qd*8];

  const short8 zero8 = {0,0,0,0,0,0,0,0};
  for (int kt = 0; kt < DFF; kt += 32){
    short8 av = aok ? *(const short8*)(Ap + kt) : zero8;
    float4 w0 = *(const float4*)(Wp + kt);
    float4 w1v= *(const float4*)(Wp + kt + 4);
    short8 wvv;
    wvv[0]=(short)f2bf(w0.x); wvv[1]=(short)f2bf(w0.y); wvv[2]=(short)f2bf(w0.z); wvv[3]=(short)f2bf(w0.w);
    wvv[4]=(short)f2bf(w1v.x); wvv[5]=(short)f2bf(w1v.y); wvv[6]=(short)f2bf(w1v.z); wvv[7]=(short)f2bf(w1v.w);
    __syncthreads();
    *(short8*)aw = av;
    *(short8*)ww = wvv;
    __syncthreads();
    short8 af = *(const short8*)ard;
    short8 b0 = *(const short8*)(brd);
    short8 b1f= *(const short8*)(brd + 16*40);
    short8 b2f= *(const short8*)(brd + 32*40);
    short8 b3f= *(const short8*)(brd + 48*40);
    acc0 = __builtin_amdgcn_mfma_f32_16x16x32_bf16(af, b0, acc0, 0,0,0);
    acc1 = __builtin_amdgcn_mfma_f32_16x16x32_bf16(af, b1f, acc1, 0,0,0);
    acc2 = __builtin_amdgcn_mfma_f32_16x16x32_bf16(af, b2f, acc2, 0,0,0);
    acc3 = __builtin_amdgcn_mfma_f32_16x16x32_bf16(af, b3f, acc3, 0,0,0);
  }

  #pragma unroll
  for (int ct=0; ct<4; ct++){
    f32x4 a = (ct==0)?acc0:(ct==1)?acc1:(ct==2)?acc2:acc3;
    int colg = n0 + ct*16 + mr;
    float bias = b2[(size_t)e*DMODEL + colg];
    #pragma unroll
    for (int r=0;r<4;r++){
      int sl = wv*16 + qd*4 + r;
      int t = toks[sl];
      if (t < 0) continue;
      float v = a[r] + bias;
      atomicAdd(&hres[(size_t)t*DMODEL + colg], wts[sl]*v);
    }
  }
}

__global__ __launch_bounds__(256) void final_kernel(const float* __restrict__ hres,
                                                    float* __restrict__ out)
{
  int i = blockIdx.x*256 + threadIdx.x;
  out[i] = hres[i];
}

// ---------------------------------------------------------------------------
extern "C" void kernel_launch(void* const* d_in, const int* in_sizes, int n_in,
                              void* d_out, int out_size, void* d_ws, size_t ws_size,
                              hipStream_t stream)
{
  const float* x         = (const float*)d_in[0];
  const float* ln_m_g    = (const float*)d_in[1];
  const float* ln_m_b    = (const float*)d_in[2];
  const float* ln_e_g    = (const float*)d_in[3];
  const float* ln_e_b    = (const float*)d_in[4];
  const float* in_proj_w = (const float*)d_in[5];
  const float* in_proj_b = (const float*)d_in[6];
  const float* conv_w    = (const float*)d_in[7];
  const float* conv_b    = (const float*)d_in[8];
  const float* x_proj_w  = (const float*)d_in[9];
  const float* dt_proj_w = (const float*)d_in[10];
  const float* dt_proj_b = (const float*)d_in[11];
  const float* A_log     = (const float*)d_in[12];
  const float* D_skip    = (const float*)d_in[13];
  const float* out_proj_w= (const float*)d_in[14];
  const float* router_w  = (const float*)d_in[15];
  const float* w1        = (const float*)d_in[16];
  const float* b1        = (const float*)d_in[17];
  const float* w2        = (const float*)d_in[18];
  const float* b2        = (const float*)d_in[19];

  // Workspace map (fp32 unless noted), peak unchanged (~97.6 MB + misc):
  //   [0,64M)       xz [4096,4096]; after scan dead -> hres [0,16M), H1 [16M,48M)
  //                 Wo hi/lo bf16 overlay at [32M,48M) (after scan, before H1)
  //   [64M,96M)     xc [4096,2048] -> y in-place; Wi hi/lo overlay (before conv)
  //   [96M,97.5M)   proj [4096,96]
  //   [97.5M,...)   misc (counters + buckets, ~132 KB)
  // d_out[0,16M) scratch: hn (LN output) -> Wx/Wd hi/lo -> P/Q/Hs during scan.
  char* ws = (char*)d_ws;
  float* xz   = (float*)(ws + 0);
  float* xc   = (float*)(ws + 67108864ull);
  float* proj = (float*)(ws + 100663296ull);
  char*  misc = ws + 102236160ull;
  float* hres = (float*)(ws + 0);
  unsigned short* H1 = (unsigned short*)(ws + 16777216ull);
  float* hn   = (float*)d_out;
  float* Pbuf = (float*)d_out;                 // 1M floats
  float* Qbuf = (float*)d_out + (1u<<20);      // 1M floats
  float* Hsb  = (float*)d_out + (2u<<20);      // 1M floats

  // pre-split weight overlays (hi/lo bf16):
  unsigned short* Wi_hi = (unsigned short*)(ws + 67108864ull);  // xc region, dead until conv
  unsigned short* Wi_lo = Wi_hi + 4194304;                      // 4096*1024
  unsigned short* Wo_hi = (unsigned short*)(ws + 33554432ull);  // xz[32M,48M), dead after scan
  unsigned short* Wo_lo = Wo_hi + 2097152;                      // 1024*2048
  unsigned short* Wx_hi = (unsigned short*)d_out;               // hn dead after in_proj gemm
  unsigned short* Wx_lo = Wx_hi + 196608;                       // 96*2048
  unsigned short* Wd_hi = Wx_lo + 196608;
  unsigned short* Wd_lo = Wd_hi + 131072;                       // 2048*64

  int*   cnt      = (int*)(misc);
  int*   fill     = (int*)(misc + 64);
  int*   offp     = (int*)(misc + 128);
  int*   tok_e0   = (int*)(misc + 1024);
  int*   tok_e1   = (int*)(misc + 1024 + 16384);
  float* tok_w0   = (float*)(misc + 1024 + 32768);
  float* tok_w1   = (float*)(misc + 1024 + 49152);
  int*   slot_tok = (int*)(misc + 1024 + 65536);
  float* slot_w   = (float*)(misc + 1024 + 98304);
  float* out_h    = (float*)d_out;
  float* probs_out= (float*)d_out + 4194304;

  zero_kernel<<<1, 64, 0, stream>>>(cnt);

  // ---- Mamba branch ----
  split_kernel<<<4096, 256, 0, stream>>>(in_proj_w, Wi_hi, Wi_lo, 4194304);
  ln_kernel<<<NTOK, 256, 0, stream>>>(x, ln_m_g, ln_m_b, hn);
  // in_proj: [4096,4096] = hn[4096,1024] @ W^T (+bias) -> xz
  gemm_mfma<0,128><<<dim3(64, 32), 256, 0, stream>>>(
      hn, DMODEL, Wi_hi, Wi_lo, DMODEL, NTOK, 4096, DMODEL,
      in_proj_b, nullptr, 0, xz, 4096);
  // hn dead now: split x_proj_w / dt_proj_w into d_out scratch
  split_kernel<<<192, 256, 0, stream>>>(x_proj_w, Wx_hi, Wx_lo, 196608);
  split_kernel<<<128, 256, 0, stream>>>(dt_proj_w, Wd_hi, Wd_lo, 131072);
  conv_kernel<<<NTOK*DINNER/256, 256, 0, stream>>>(xz, conv_w, conv_b, xc);
  // x_proj: proj[4096,96] = xc @ W^T  (BM=64 for 128-block grid on skinny N)
  gemm_mfma<1,64><<<dim3(2, 64), 256, 0, stream>>>(
      xc, DINNER, Wx_hi, Wx_lo, DINNER, NTOK, 96, DINNER,
      nullptr, nullptr, 0, proj, 96);
  // dt (softplus) -> dead xi half of xz (ldo = 4096)
  gemm_mfma<2,128><<<dim3(32, 32), 256, 0, stream>>>(
      proj, 96, Wd_hi, Wd_lo, DTRANK, NTOK, DINNER, DTRANK,
      dt_proj_b, nullptr, 0, xz, 4096);
  // chunked parallel scan (P/Q/Hs in dead hn region of d_out)
  scan_partial<<<dim3(DINNER/16, NCHUNK, 2), 256, 0, stream>>>(
      xz, xc, proj, A_log, Pbuf, Qbuf);
  scan_combine<<<256, 256, 0, stream>>>(Pbuf, Qbuf, Hsb);
  scan_final<<<dim3(DINNER/16, NCHUNK, 2), 256, 0, stream>>>(
      xz, xc, proj, A_log, D_skip, Hsb);
  // xz dt/z consumed: split out_proj_w into dead xz[32M,48M)
  split_kernel<<<2048, 256, 0, stream>>>(out_proj_w, Wo_hi, Wo_lo, 2097152);
  // out_proj + residual x -> hres
  gemm_mfma<3,128><<<dim3(16, 32), 256, 0, stream>>>(
      xc, DINNER, Wo_hi, Wo_lo, DINNER, NTOK, DMODEL, DINNER,
      nullptr, x, DMODEL, hres, DMODEL);

  // ---- MoE branch ----
  ln_kernel<<<NTOK, 256, 0, stream>>>(hres, ln_e_g, ln_e_b, hn);
  router_kernel<<<NTOK, 256, 0, stream>>>(hn, router_w, probs_out, cnt,
                                          tok_e0, tok_e1, tok_w0, tok_w1);
  prefix_kernel<<<1, 64, 0, stream>>>(cnt, offp, fill);
  fill_kernel<<<NTOK/256, 256, 0, stream>>>(tok_e0, tok_e1, tok_w0, tok_w1,
                                            offp, fill, slot_tok, slot_w);
  moe_gemm1<<<dim3(DFF/64, 64, NEXP), 256, 0, stream>>>(
      hn, w1, b1, cnt, offp, slot_tok, H1);
  moe_gemm2<<<dim3(DMODEL/64, 64, NEXP), 256, 0, stream>>>(
      H1, w2, b2, cnt, offp, slot_tok, slot_w, hres);

  final_kernel<<<NTOK*DMODEL/256, 256, 0, stream>>>(hres, out_h);
}

// Round 2
// 1090.679 us; speedup vs baseline: 1.6638x; 1.1946x over previous
//
#include <hip/hip_runtime.h>
#include <hip/hip_bf16.h>
#include <math.h>

#define NTOK   4096   // B*T
#define TSEQ   2048
#define DMODEL 1024
#define DINNER 2048
#define NSTATE 16
#define DTRANK 64
#define NEXP   8
#define DFF    2048
#define NCHUNK 32
#define CLEN   64     // TSEQ / NCHUNK

typedef __attribute__((ext_vector_type(8))) short short8;
typedef __attribute__((ext_vector_type(4))) float f32x4;

__device__ __forceinline__ float fast_rcp(float x){ return __builtin_amdgcn_rcpf(x); }
// fast silu: __expf -> v_mul+v_exp_f32; rcp 1ulp. Downstream bf16 noise dominates.
__device__ __forceinline__ float siluf(float x){ return x * fast_rcp(1.f + __expf(-x)); }

// fp32 -> bf16 (round-to-nearest-even), as raw ushort
__device__ __forceinline__ unsigned short f2bf(float x){
  unsigned int u = __float_as_uint(x);
  unsigned int r = (u + 0x7FFFu + ((u >> 16) & 1u)) >> 16;
  return (unsigned short)r;
}

// split fp32 -> (hi, lo) bf16 pair: x ~= hi + lo, |err| <= 2^-18 |x|
__device__ __forceinline__ void split4(float4 a, unsigned short* hi, unsigned short* lo){
  float av[4] = {a.x, a.y, a.z, a.w};
  #pragma unroll
  for (int j=0;j<4;j++){
    unsigned short hu = f2bf(av[j]);
    float hf = __uint_as_float((unsigned int)hu << 16);
    hi[j] = hu;
    lo[j] = f2bf(av[j] - hf);
  }
}

// ---------------------------------------------------------------------------
// zero counters (cnt/fill/off = 64 ints)
// ---------------------------------------------------------------------------
__global__ void zero_kernel(int* __restrict__ p){ p[threadIdx.x] = 0; }

// ---------------------------------------------------------------------------
// Pre-split an fp32 array into hi/lo bf16 arrays. n multiple of 1024.
// ---------------------------------------------------------------------------
__global__ __launch_bounds__(256) void split_kernel(
    const float* __restrict__ in, unsigned short* __restrict__ hi,
    unsigned short* __restrict__ lo, int n)
{
  int i = (blockIdx.x*256 + threadIdx.x)*4;
  if (i >= n) return;
  float4 v = *(const float4*)(in + i);
  unsigned short ht[4], lt[4];
  split4(v, ht, lt);
  uint2 hw, lw;
  hw.x = (unsigned)ht[0] | ((unsigned)ht[1]<<16);
  hw.y = (unsigned)ht[2] | ((unsigned)ht[3]<<16);
  lw.x = (unsigned)lt[0] | ((unsigned)lt[1]<<16);
  lw.y = (unsigned)lt[2] | ((unsigned)lt[3]<<16);
  *(uint2*)(hi+i) = hw;
  *(uint2*)(lo+i) = lw;
}

// ---------------------------------------------------------------------------
// Split-bf16 MFMA GEMM: C[M,N] = A[M,K] @ W[N,K]^T (+epilogue), ~fp32 accuracy.
// A is fp32 (split to hi/lo in-kernel); W is pre-split (Whi/Wlo bf16 ushort).
// Per product: ah*bh + al*bh + ah*bl (drop al*bl, <=2^-18 rel) in fp32 acc.
// Tile BM x 64, BK=32, 256 threads / 4 waves; wave owns BM/4 rows x 64 cols.
// EPI: 0 = +bias | 1 = plain | 2 = +bias,softplus | 3 = +resid
// ---------------------------------------------------------------------------
template<int EPI, int BM>
__global__ __launch_bounds__(256) void gemm_mfma(
    const float* __restrict__ A, int lda,
    const unsigned short* __restrict__ Whi, const unsigned short* __restrict__ Wlo, int ldw,
    int M, int N, int K,
    const float* __restrict__ bias,
    const float* __restrict__ resid, int ldr,
    float* __restrict__ out, int ldo)
{
  constexpr int TA = BM/8;      // fp32 A elems staged per thread (16 or 8)
  constexpr int RG = BM/64;     // 16-row groups per wave (2 or 1)
  const int tid = threadIdx.x;
  const int m0 = blockIdx.y * BM;
  const int n0 = blockIdx.x * 64;

  __shared__ __align__(16) unsigned short Ahs[BM*40];
  __shared__ __align__(16) unsigned short Als[BM*40];
  __shared__ __align__(16) unsigned short Whs[64*40];
  __shared__ __align__(16) unsigned short Wls[64*40];

  const int arow = tid / (32/TA);
  const int ak   = (tid % (32/TA)) * TA;
  const int wrow = tid >> 2;
  const int wk   = (tid & 3) * 8;

  const float* Ap = A + (size_t)(m0 + arow)*lda + ak;
  const bool wok = (n0 + wrow) < N;
  const unsigned short* Whp = Whi + (size_t)(n0 + wrow)*ldw + wk;
  const unsigned short* Wlp = Wlo + (size_t)(n0 + wrow)*ldw + wk;

  const int lane = tid & 63;
  const int wv   = tid >> 6;
  const int qd   = lane >> 4;
  const int mr   = lane & 15;

  f32x4 acc[RG][4];
  #pragma unroll
  for (int rg=0; rg<RG; rg++)
    #pragma unroll
    for (int ct=0; ct<4; ct++) acc[rg][ct] = (f32x4){0.f,0.f,0.f,0.f};

  const unsigned short* ardh = &Ahs[(wv*(16*RG) + mr)*40 + qd*8];
  const unsigned short* ardl = &Als[(wv*(16*RG) + mr)*40 + qd*8];
  const unsigned short* brdh = &Whs[mr*40 + qd*8];
  const unsigned short* brdl = &Wls[mr*40 + qd*8];

  const short8 z8 = {0,0,0,0,0,0,0,0};

  for (int kt = 0; kt < K; kt += 32){
    short8 ahi[TA/8], alo[TA/8];
    #pragma unroll
    for (int h=0; h<TA/8; h++){
      unsigned short ht[8], lt[8];
      split4(*(const float4*)(Ap + kt + h*8),     ht,   lt);
      split4(*(const float4*)(Ap + kt + h*8 + 4), ht+4, lt+4);
      #pragma unroll
      for (int j=0;j<8;j++){ ahi[h][j]=(short)ht[j]; alo[h][j]=(short)lt[j]; }
    }
    short8 wh8 = wok ? *(const short8*)(Whp + kt) : z8;
    short8 wl8 = wok ? *(const short8*)(Wlp + kt) : z8;
    __syncthreads();
    #pragma unroll
    for (int h=0; h<TA/8; h++){
      *(short8*)&Ahs[arow*40 + ak + h*8] = ahi[h];
      *(short8*)&Als[arow*40 + ak + h*8] = alo[h];
    }
    *(short8*)&Whs[wrow*40 + wk] = wh8;
    *(short8*)&Wls[wrow*40 + wk] = wl8;
    __syncthreads();
    #pragma unroll
    for (int rg=0; rg<RG; rg++){
      short8 ah = *(const short8*)(ardh + rg*16*40);
      short8 al = *(const short8*)(ardl + rg*16*40);
      #pragma unroll
      for (int ct=0; ct<4; ct++){
        short8 bh = *(const short8*)(brdh + ct*16*40);
        short8 bl = *(const short8*)(brdl + ct*16*40);
        f32x4 t = acc[rg][ct];
        t = __builtin_amdgcn_mfma_f32_16x16x32_bf16(ah, bh, t, 0,0,0);
        t = __builtin_amdgcn_mfma_f32_16x16x32_bf16(al, bh, t, 0,0,0);
        t = __builtin_amdgcn_mfma_f32_16x16x32_bf16(ah, bl, t, 0,0,0);
        acc[rg][ct] = t;
      }
    }
  }

  #pragma unroll
  for (int rg=0; rg<RG; rg++){
    #pragma unroll
    for (int ct=0; ct<4; ct++){
      int colg = n0 + ct*16 + mr;
      if (colg >= N) continue;
      float bias_v = (EPI==0 || EPI==2) ? bias[colg] : 0.f;
      #pragma unroll
      for (int r=0;r<4;r++){
        int rowg = m0 + wv*(16*RG) + rg*16 + qd*4 + r;
        float v = acc[rg][ct][r];
        if (EPI == 0){ v += bias_v; }
        else if (EPI == 2){ v += bias_v; v = (v > 20.f) ? v : log1pf(expf(v)); }
        else if (EPI == 3){ v += resid[(size_t)rowg*ldr + colg]; }
        out[(size_t)rowg*ldo + colg] = v;
      }
    }
  }
}

// ---------------------------------------------------------------------------
// LayerNorm over D=1024, one token per 256-thread block (all fp32)
// ---------------------------------------------------------------------------
__global__ __launch_bounds__(256) void ln_kernel(
    const float* __restrict__ x, const float* __restrict__ g, const float* __restrict__ b,
    float* __restrict__ out)
{
  int tok = blockIdx.x;
  int tid = threadIdx.x;
  const float* row = x + (size_t)tok * DMODEL;
  float v[4];
  float s = 0.f, sq = 0.f;
  #pragma unroll
  for (int j=0;j<4;j++){
    v[j] = row[j*256 + tid];
    s += v[j]; sq += v[j]*v[j];
  }
  #pragma unroll
  for (int o=1;o<64;o<<=1){ s += __shfl_xor(s,o,64); sq += __shfl_xor(sq,o,64); }
  __shared__ float ss[4], ssq[4];
  int wid = tid >> 6, lane = tid & 63;
  if (lane == 0){ ss[wid]=s; ssq[wid]=sq; }
  __syncthreads();
  s  = ss[0]+ss[1]+ss[2]+ss[3];
  sq = ssq[0]+ssq[1]+ssq[2]+ssq[3];
  float mu = s * (1.f/DMODEL);
  float var = sq * (1.f/DMODEL) - mu*mu;
  float rs = rsqrtf(var + 1e-5f);
  #pragma unroll
  for (int j=0;j<4;j++){
    int d = j*256 + tid;
    out[(size_t)tok*DMODEL + d] = (v[j]-mu)*rs*g[d] + b[d];
  }
}

// ---------------------------------------------------------------------------
// Causal depthwise conv (KC=4) + SiLU.  xi = xz[:, 0:2048] (row stride 4096)
// ---------------------------------------------------------------------------
__global__ __launch_bounds__(256) void conv_kernel(
    const float* __restrict__ xz, const float* __restrict__ cw,
    const float* __restrict__ cb, float* __restrict__ xc)
{
  int i = blockIdx.x*256 + threadIdx.x;      // < NTOK*DINNER
  int tok = i >> 11;
  int ch  = i & 2047;
  int t   = tok & (TSEQ-1);
  int b   = tok >> 11;
  float acc = cb[ch];
  #pragma unroll
  for (int k=0;k<4;k++){
    int tt = t + k - 3;
    if (tt >= 0)
      acc = fmaf(cw[ch*4 + k], xz[(size_t)((b<<11)+tt)*4096 + ch], acc);
  }
  xc[i] = siluf(acc);
}

// ---------------------------------------------------------------------------
// Chunked parallel selective scan, lane-per-channel layout:
// one lane owns one channel, h[16] states in registers; B/C are block-uniform
// (scalar loads); n-reduction = register FMAs (no shuffles); fast v_exp.
// 3 passes: partial (per-chunk h, decay P), combine (in-place: Hs over P),
// final (recompute with injected state + C-contraction + z-gate).
// ---------------------------------------------------------------------------
__global__ __launch_bounds__(256) void scan_partial(
    const float* __restrict__ xz, const float* __restrict__ xc,
    const float* __restrict__ proj, const float* __restrict__ A_log,
    float* __restrict__ P, float* __restrict__ Q)
{
  int tid = threadIdx.x;
  int ch  = blockIdx.x*256 + tid;       // grid.x = DINNER/256
  int c   = blockIdx.y;
  int b   = blockIdx.z;
  float A[16];
  #pragma unroll
  for (int n=0;n<16;n++) A[n] = -expf(A_log[ch*NSTATE + n]);
  float h[16];
  #pragma unroll
  for (int n=0;n<16;n++) h[n] = 0.f;
  float sdt = 0.f;
  int tok0 = (b<<11) + c*CLEN;
  // 1-deep prefetch of per-lane streams
  float dtv = xz[(size_t)tok0*4096 + ch];
  float xt  = xc[(size_t)tok0*2048 + ch];
  for (int i=0;i<CLEN;i++){
    int tn = tok0 + ((i+1 < CLEN) ? i+1 : i);
    float dtv_n = xz[(size_t)tn*4096 + ch];
    float xt_n  = xc[(size_t)tn*2048 + ch];
    const float4* pB = (const float4*)(proj + (size_t)(tok0+i)*96 + 64);
    float Bv[16];
    *(float4*)&Bv[0]  = pB[0];
    *(float4*)&Bv[4]  = pB[1];
    *(float4*)&Bv[8]  = pB[2];
    *(float4*)&Bv[12] = pB[3];
    float dxt = dtv*xt;
    sdt += dtv;
    #pragma unroll
    for (int n=0;n<16;n++){
      float dA = __expf(dtv*A[n]);
      h[n] = fmaf(dA, h[n], dxt*Bv[n]);
    }
    dtv = dtv_n; xt = xt_n;
  }
  size_t base = ((((size_t)(b*NCHUNK + c))<<11 | ch)<<4);
  #pragma unroll
  for (int n=0;n<16;n++){
    P[base+n] = __expf(A[n]*sdt);
    Q[base+n] = h[n];
  }
}

// In-place combine: PH holds P on entry, Hs (incoming state per chunk) on exit.
__global__ __launch_bounds__(256) void scan_combine(
    const float* __restrict__ Q, float* PH)
{
  int g = blockIdx.x*256 + threadIdx.x;   // 65536 = b*32768 + ch*16 + n
  int n = g & 15, ch = (g>>4) & 2047, b = g>>15;
  float hs = 0.f;
  for (int c=0;c<NCHUNK;c++){
    size_t idx = ((((size_t)(b*NCHUNK + c))<<11 | ch)<<4) | n;
    float pv = PH[idx];
    float qv = Q[idx];
    PH[idx] = hs;
    hs = fmaf(pv, hs, qv);
  }
}

__global__ __launch_bounds__(256) void scan_final(
    const float* __restrict__ xz, float* __restrict__ xc,
    const float* __restrict__ proj, const float* __restrict__ A_log,
    const float* __restrict__ Dskip, const float* __restrict__ Hs)
{
  int tid = threadIdx.x;
  int ch  = blockIdx.x*256 + tid;
  int c   = blockIdx.y;
  int b   = blockIdx.z;
  float A[16];
  #pragma unroll
  for (int n=0;n<16;n++) A[n] = -expf(A_log[ch*NSTATE + n]);
  float Dv = Dskip[ch];
  size_t base = ((((size_t)(b*NCHUNK + c))<<11 | ch)<<4);
  float h[16];
  #pragma unroll
  for (int n=0;n<16;n++) h[n] = Hs[base+n];
  int tok0 = (b<<11) + c*CLEN;
  float dtv = xz[(size_t)tok0*4096 + ch];
  float xt  = xc[(size_t)tok0*2048 + ch];
  float zv  = xz[(size_t)tok0*4096 + 2048 + ch];
  for (int i=0;i<CLEN;i++){
    int tn = tok0 + ((i+1 < CLEN) ? i+1 : i);
    float dtv_n = xz[(size_t)tn*4096 + ch];
    float xt_n  = xc[(size_t)tn*2048 + ch];
    float zv_n  = xz[(size_t)tn*4096 + 2048 + ch];
    const float4* pB = (const float4*)(proj + (size_t)(tok0+i)*96 + 64);
    float Bv[16], Cv[16];
    *(float4*)&Bv[0]  = pB[0];
    *(float4*)&Bv[4]  = pB[1];
    *(float4*)&Bv[8]  = pB[2];
    *(float4*)&Bv[12] = pB[3];
    *(float4*)&Cv[0]  = pB[4];
    *(float4*)&Cv[4]  = pB[5];
    *(float4*)&Cv[8]  = pB[6];
    *(float4*)&Cv[12] = pB[7];
    float dxt = dtv*xt;
    float y = xt*Dv;
    #pragma unroll
    for (int n=0;n<16;n++){
      float dA = __expf(dtv*A[n]);
      h[n] = fmaf(dA, h[n], dxt*Bv[n]);
      y = fmaf(h[n], Cv[n], y);
    }
    xc[(size_t)(tok0+i)*2048 + ch] = y * siluf(zv);
    dtv = dtv_n; xt = xt_n; zv = zv_n;
  }
}

// ---------------------------------------------------------------------------
// Router: logits, softmax (-> d_out probs), top-2, atomic expert counts
// (kept precise: top-k decisions are tie-sensitive)
// ---------------------------------------------------------------------------
__global__ __launch_bounds__(256) void router_kernel(
    const float* __restrict__ hmoe, const float* __restrict__ rw,
    float* __restrict__ probs_out, int* __restrict__ cnt,
    int* __restrict__ tok_e0, int* __restrict__ tok_e1,
    float* __restrict__ tok_w0, float* __restrict__ tok_w1)
{
  int tok = blockIdx.x;
  int tid = threadIdx.x;
  int e = tid >> 5, l = tid & 31;
  float s = 0.f;
  const float* row = hmoe + (size_t)tok*DMODEL;
  const float* wr  = rw + (size_t)e*DMODEL;
  for (int d=l; d<DMODEL; d+=32) s = fmaf(row[d], wr[d], s);
  #pragma unroll
  for (int o=1;o<32;o<<=1) s += __shfl_xor(s,o,64);
  __shared__ float lg[8];
  if (l==0) lg[e]=s;
  __syncthreads();
  if (tid==0){
    float mx = lg[0];
    for (int k=1;k<8;k++) mx = fmaxf(mx, lg[k]);
    float pe[8]; float den=0.f;
    for (int k=0;k<8;k++){ pe[k]=expf(lg[k]-mx); den+=pe[k]; }
    float inv = 1.f/den;
    for (int k=0;k<8;k++) probs_out[tok*8+k] = pe[k]*inv;
    int i0=0;
    for (int k=1;k<8;k++) if (pe[k] > pe[i0]) i0=k;
    int i1 = (i0==0)?1:0;
    for (int k=0;k<8;k++) if (k!=i0 && pe[k] > pe[i1]) i1=k;
    float v0=pe[i0], v1=pe[i1], sw=v0+v1;
    tok_e0[tok]=i0; tok_e1[tok]=i1;
    tok_w0[tok]=v0/sw; tok_w1[tok]=v1/sw;
    atomicAdd(&cnt[i0],1); atomicAdd(&cnt[i1],1);
  }
}

__global__ void prefix_kernel(const int* cnt, int* off, int* fill){
  if (threadIdx.x==0){
    int s=0;
    for (int e=0;e<NEXP;e++){ off[e]=s; s+=cnt[e]; fill[e]=0; }
  }
}

__global__ __launch_bounds__(256) void fill_kernel(
    const int* tok_e0, const int* tok_e1, const float* tok_w0, const float* tok_w1,
    const int* off, int* fill, int* slot_tok, float* slot_w)
{
  int tok = blockIdx.x*256 + threadIdx.x;
  int e0=tok_e0[tok], e1=tok_e1[tok];
  int p0 = atomicAdd(&fill[e0],1); int s0 = off[e0]+p0;
  slot_tok[s0]=tok; slot_w[s0]=tok_w0[tok];
  int p1 = atomicAdd(&fill[e1],1); int s1 = off[e1]+p1;
  slot_tok[s1]=tok; slot_w[s1]=tok_w1[tok];
}

// ---------------------------------------------------------------------------
// MoE GEMM1 via bf16 MFMA: H1[slot,DFF] = silu(hmoe[tok] @ w1[e]^T + b1[e])
// ---------------------------------------------------------------------------
__global__ __launch_bounds__(256) void moe_gemm1(
    const float* __restrict__ hmoe, const float* __restrict__ w1, const float* __restrict__ b1,
    const int* __restrict__ cnt, const int* __restrict__ off,
    const int* __restrict__ slot_tok, unsigned short* __restrict__ H1)
{
  int e = blockIdx.z;
  int c = cnt[e];
  int r0 = blockIdx.y*64;
  if (r0 >= c) return;
  int base = off[e];
  int tid = threadIdx.x;
  __shared__ int toks[64];
  if (tid < 64) toks[tid] = (r0 + tid < c) ? slot_tok[base + r0 + tid] : -1;
  __shared__ __align__(16) unsigned short As[64*40];
  __shared__ __align__(16) unsigned short Ws[64*40];
  __syncthreads();

  const int n0   = blockIdx.x*64;
  const int arow = tid >> 2;
  const int kq   = (tid & 3) * 8;
  const int tok  = toks[arow];
  const float* Ap = hmoe + (size_t)(tok < 0 ? 0 : tok)*DMODEL + kq;
  const bool aok  = (tok >= 0);
  const float* Wp = w1 + (size_t)e*DFF*DMODEL + (size_t)(n0+arow)*DMODEL + kq;

  const int lane = tid & 63;
  const int wv   = tid >> 6;
  const int qd   = lane >> 4;
  const int mr   = lane & 15;

  f32x4 acc0={0,0,0,0}, acc1={0,0,0,0}, acc2={0,0,0,0}, acc3={0,0,0,0};

  unsigned short* aw = &As[arow*40 + kq];
  unsigned short* ww = &Ws[arow*40 + kq];
  const unsigned short* ard = &As[(wv*16 + mr)*40 + qd*8];
  const unsigned short* brd = &Ws[mr*40 + qd*8];

  for (int kt = 0; kt < DMODEL; kt += 32){
    float4 a0 = aok ? *(const float4*)(Ap + kt)     : make_float4(0,0,0,0);
    float4 a1 = aok ? *(const float4*)(Ap + kt + 4) : make_float4(0,0,0,0);
    float4 w0 = *(const float4*)(Wp + kt);
    float4 w1v= *(const float4*)(Wp + kt + 4);
    short8 av, wvv;
    av[0]=(short)f2bf(a0.x); av[1]=(short)f2bf(a0.y); av[2]=(short)f2bf(a0.z); av[3]=(short)f2bf(a0.w);
    av[4]=(short)f2bf(a1.x); av[5]=(short)f2bf(a1.y); av[6]=(short)f2bf(a1.z); av[7]=(short)f2bf(a1.w);
    wvv[0]=(short)f2bf(w0.x); wvv[1]=(short)f2bf(w0.y); wvv[2]=(short)f2bf(w0.z); wvv[3]=(short)f2bf(w0.w);
    wvv[4]=(short)f2bf(w1v.x); wvv[5]=(short)f2bf(w1v.y); wvv[6]=(short)f2bf(w1v.z); wvv[7]=(short)f2bf(w1v.w);
    __syncthreads();
    *(short8*)aw = av;
    *(short8*)ww = wvv;
    __syncthreads();
    short8 af = *(const short8*)ard;
    short8 b0 = *(const short8*)(brd);
    short8 b1f= *(const short8*)(brd + 16*40);
    short8 b2f= *(const short8*)(brd + 32*40);
    short8 b3f= *(const short8*)(brd + 48*40);
    acc0 = __builtin_amdgcn_mfma_f32_16x16x32_bf16(af, b0, acc0, 0,0,0);
    acc1 = __builtin_amdgcn_mfma_f32_16x16x32_bf16(af, b1f, acc1, 0,0,0);
    acc2 = __builtin_amdgcn_mfma_f32_16x16x32_bf16(af, b2f, acc2, 0,0,0);
    acc3 = __builtin_amdgcn_mfma_f32_16x16x32_bf16(af, b3f, acc3, 0,0,0);
  }

  #pragma unroll
  for (int ct=0; ct<4; ct++){
    f32x4 a = (ct==0)?acc0:(ct==1)?acc1:(ct==2)?acc2:acc3;
    int colg = n0 + ct*16 + mr;
    float bias = b1[(size_t)e*DFF + colg];
    #pragma unroll
    for (int r=0;r<4;r++){
      int sl = wv*16 + qd*4 + r;
      if (toks[sl] < 0) continue;
      float v = a[r] + bias;
      H1[(size_t)(base + r0 + sl)*DFF + colg] = f2bf(siluf(v));
    }
  }
}

// ---------------------------------------------------------------------------
// MoE GEMM2 via bf16 MFMA: hres[tok] += w_slot*(H1[slot] @ w2[e]^T + b2[e])
// ---------------------------------------------------------------------------
__global__ __launch_bounds__(256) void moe_gemm2(
    const unsigned short* __restrict__ H1, const float* __restrict__ w2,
    const float* __restrict__ b2,
    const int* __restrict__ cnt, const int* __restrict__ off,
    const int* __restrict__ slot_tok, const float* __restrict__ slot_w,
    float* __restrict__ hres)
{
  int e = blockIdx.z;
  int c = cnt[e];
  int r0 = blockIdx.y*64;
  if (r0 >= c) return;
  int base = off[e];
  int tid = threadIdx.x;
  __shared__ int toks[64];
  __shared__ float wts[64];
  if (tid < 64){
    int r = r0 + tid;
    toks[tid] = (r<c) ? slot_tok[base+r] : -1;
    wts[tid]  = (r<c) ? slot_w[base+r] : 0.f;
  }
  __shared__ __align__(16) unsigned short As[64*40];
  __shared__ __align__(16) unsigned short Ws[64*40];
  __syncthreads();

  const int n0   = blockIdx.x*64;
  const int arow = tid >> 2;
  const int kq   = (tid & 3) * 8;
  const bool aok = (toks[arow] >= 0);
  const unsigned short* Ap = H1 + (size_t)(base + r0 + (aok ? arow : 0))*DFF + kq;
  const float* Wp = w2 + (size_t)e*DMODEL*DFF + (size_t)(n0+arow)*DFF + kq;

  const int lane = tid & 63;
  const int wv   = tid >> 6;
  const int qd   = lane >> 4;
  const int mr   = lane & 15;

  f32x4 acc0={0,0,0,0}, acc1={0,0,0,0}, acc2={0,0,0,0}, acc3={0,0,0,0};

  unsigned short* aw = &As[arow*40 + kq];
  unsigned short* ww = &Ws[arow*40 + kq];
  const unsigned short* ard = &As[(wv*16 + mr)*40 + qd*8];
  const unsigned short* brd = &Ws[mr*40 + qd*8];

  const short8 zero8 = {0,0,0,0,0,0,0,0};
  for (int kt = 0; kt < DFF; kt += 32){
    short8 av = aok ? *(const short8*)(Ap + kt) : zero8;
    float4 w0 = *(const float4*)(Wp + kt);
    float4 w1v= *(const float4*)(Wp + kt + 4);
    short8 wvv;
    wvv[0]=(short)f2bf(w0.x); wvv[1]=(short)f2bf(w0.y); wvv[2]=(short)f2bf(w0.z); wvv[3]=(short)f2bf(w0.w);
    wvv[4]=(short)f2bf(w1v.x); wvv[5]=(short)f2bf(w1v.y); wvv[6]=(short)f2bf(w1v.z); wvv[7]=(short)f2bf(w1v.w);
    __syncthreads();
    *(short8*)aw = av;
    *(short8*)ww = wvv;
    __syncthreads();
    short8 af = *(const short8*)ard;
    short8 b0 = *(const short8*)(brd);
    short8 b1f= *(const short8*)(brd + 16*40);
    short8 b2f= *(const short8*)(brd + 32*40);
    short8 b3f= *(const short8*)(brd + 48*40);
    acc0 = __builtin_amdgcn_mfma_f32_16x16x32_bf16(af, b0, acc0, 0,0,0);
    acc1 = __builtin_amdgcn_mfma_f32_16x16x32_bf16(af, b1f, acc1, 0,0,0);
    acc2 = __builtin_amdgcn_mfma_f32_16x16x32_bf16(af, b2f, acc2, 0,0,0);
    acc3 = __builtin_amdgcn_mfma_f32_16x16x32_bf16(af, b3f, acc3, 0,0,0);
  }

  #pragma unroll
  for (int ct=0; ct<4; ct++){
    f32x4 a = (ct==0)?acc0:(ct==1)?acc1:(ct==2)?acc2:acc3;
    int colg = n0 + ct*16 + mr;
    float bias = b2[(size_t)e*DMODEL + colg];
    #pragma unroll
    for (int r=0;r<4;r++){
      int sl = wv*16 + qd*4 + r;
      int t = toks[sl];
      if (t < 0) continue;
      float v = a[r] + bias;
      atomicAdd(&hres[(size_t)t*DMODEL + colg], wts[sl]*v);
    }
  }
}

__global__ __launch_bounds__(256) void final_kernel(const float* __restrict__ hres,
                                                    float* __restrict__ out)
{
  int i = blockIdx.x*256 + threadIdx.x;
  out[i] = hres[i];
}

// ---------------------------------------------------------------------------
extern "C" void kernel_launch(void* const* d_in, const int* in_sizes, int n_in,
                              void* d_out, int out_size, void* d_ws, size_t ws_size,
                              hipStream_t stream)
{
  const float* x         = (const float*)d_in[0];
  const float* ln_m_g    = (const float*)d_in[1];
  const float* ln_m_b    = (const float*)d_in[2];
  const float* ln_e_g    = (const float*)d_in[3];
  const float* ln_e_b    = (const float*)d_in[4];
  const float* in_proj_w = (const float*)d_in[5];
  const float* in_proj_b = (const float*)d_in[6];
  const float* conv_w    = (const float*)d_in[7];
  const float* conv_b    = (const float*)d_in[8];
  const float* x_proj_w  = (const float*)d_in[9];
  const float* dt_proj_w = (const float*)d_in[10];
  const float* dt_proj_b = (const float*)d_in[11];
  const float* A_log     = (const float*)d_in[12];
  const float* D_skip    = (const float*)d_in[13];
  const float* out_proj_w= (const float*)d_in[14];
  const float* router_w  = (const float*)d_in[15];
  const float* w1        = (const float*)d_in[16];
  const float* b1        = (const float*)d_in[17];
  const float* w2        = (const float*)d_in[18];
  const float* b2        = (const float*)d_in[19];

  // Workspace map (fp32 unless noted):
  //   [0,64M)       xz [4096,4096]; after scan dead -> hres [0,16M), H1 [16M,48M)
  //                 Wo hi/lo bf16 overlay at [32M,48M) (after scan, before H1)
  //   [64M,96M)     xc [4096,2048] -> y in-place; Wi hi/lo overlay (before conv)
  //   [96M,97.5M)   proj [4096,96]
  //   [97.5M,...)   misc (counters + buckets, ~132 KB)
  // d_out scratch timeline: hn (LN out) + Wx/Wd splits -> P/Q (NCHUNK=32:
  // 8.39MB each; PH in-place becomes Hs in combine; total 16.78MB <= 16.9MB)
  // -> hn again (MoE LN) -> final h + probs.
  char* ws = (char*)d_ws;
  float* xz   = (float*)(ws + 0);
  float* xc   = (float*)(ws + 67108864ull);
  float* proj = (float*)(ws + 100663296ull);
  char*  misc = ws + 102236160ull;
  float* hres = (float*)(ws + 0);
  unsigned short* H1 = (unsigned short*)(ws + 16777216ull);
  float* hn   = (float*)d_out;
  float* Pbuf = (float*)d_out;                 // 2M floats (P, then Hs in-place)
  float* Qbuf = (float*)d_out + (2u<<20);      // 2M floats

  // pre-split weight overlays (hi/lo bf16):
  unsigned short* Wi_hi = (unsigned short*)(ws + 67108864ull);  // xc region, dead until conv
  unsigned short* Wi_lo = Wi_hi + 4194304;                      // 4096*1024
  unsigned short* Wo_hi = (unsigned short*)(ws + 33554432ull);  // xz[32M,48M), dead after scan
  unsigned short* Wo_lo = Wo_hi + 2097152;                      // 1024*2048
  unsigned short* Wx_hi = (unsigned short*)d_out;               // hn dead after in_proj gemm
  unsigned short* Wx_lo = Wx_hi + 196608;                       // 96*2048
  unsigned short* Wd_hi = Wx_lo + 196608;
  unsigned short* Wd_lo = Wd_hi + 131072;                       // 2048*64

  int*   cnt      = (int*)(misc);
  int*   fill     = (int*)(misc + 64);
  int*   offp     = (int*)(misc + 128);
  int*   tok_e0   = (int*)(misc + 1024);
  int*   tok_e1   = (int*)(misc + 1024 + 16384);
  float* tok_w0   = (float*)(misc + 1024 + 32768);
  float* tok_w1   = (float*)(misc + 1024 + 49152);
  int*   slot_tok = (int*)(misc + 1024 + 65536);
  float* slot_w   = (float*)(misc + 1024 + 98304);
  float* out_h    = (float*)d_out;
  float* probs_out= (float*)d_out + 4194304;

  zero_kernel<<<1, 64, 0, stream>>>(cnt);

  // ---- Mamba branch ----
  split_kernel<<<4096, 256, 0, stream>>>(in_proj_w, Wi_hi, Wi_lo, 4194304);
  ln_kernel<<<NTOK, 256, 0, stream>>>(x, ln_m_g, ln_m_b, hn);
  gemm_mfma<0,128><<<dim3(64, 32), 256, 0, stream>>>(
      hn, DMODEL, Wi_hi, Wi_lo, DMODEL, NTOK, 4096, DMODEL,
      in_proj_b, nullptr, 0, xz, 4096);
  split_kernel<<<192, 256, 0, stream>>>(x_proj_w, Wx_hi, Wx_lo, 196608);
  split_kernel<<<128, 256, 0, stream>>>(dt_proj_w, Wd_hi, Wd_lo, 131072);
  conv_kernel<<<NTOK*DINNER/256, 256, 0, stream>>>(xz, conv_w, conv_b, xc);
  gemm_mfma<1,64><<<dim3(2, 64), 256, 0, stream>>>(
      xc, DINNER, Wx_hi, Wx_lo, DINNER, NTOK, 96, DINNER,
      nullptr, nullptr, 0, proj, 96);
  gemm_mfma<2,128><<<dim3(32, 32), 256, 0, stream>>>(
      proj, 96, Wd_hi, Wd_lo, DTRANK, NTOK, DINNER, DTRANK,
      dt_proj_b, nullptr, 0, xz, 4096);
  // chunked parallel scan, lane-per-channel (P/Q in d_out scratch)
  scan_partial<<<dim3(DINNER/256, NCHUNK, 2), 256, 0, stream>>>(
      xz, xc, proj, A_log, Pbuf, Qbuf);
  scan_combine<<<256, 256, 0, stream>>>(Qbuf, Pbuf);
  scan_final<<<dim3(DINNER/256, NCHUNK, 2), 256, 0, stream>>>(
      xz, xc, proj, A_log, D_skip, Pbuf);
  // xz dt/z consumed: split out_proj_w into dead xz[32M,48M)
  split_kernel<<<2048, 256, 0, stream>>>(out_proj_w, Wo_hi, Wo_lo, 2097152);
  gemm_mfma<3,128><<<dim3(16, 32), 256, 0, stream>>>(
      xc, DINNER, Wo_hi, Wo_lo, DINNER, NTOK, DMODEL, DINNER,
      nullptr, x, DMODEL, hres, DMODEL);

  // ---- MoE branch ----
  ln_kernel<<<NTOK, 256, 0, stream>>>(hres, ln_e_g, ln_e_b, hn);
  router_kernel<<<NTOK, 256, 0, stream>>>(hn, router_w, probs_out, cnt,
                                          tok_e0, tok_e1, tok_w0, tok_w1);
  prefix_kernel<<<1, 64, 0, stream>>>(cnt, offp, fill);
  fill_kernel<<<NTOK/256, 256, 0, stream>>>(tok_e0, tok_e1, tok_w0, tok_w1,
                                            offp, fill, slot_tok, slot_w);
  moe_gemm1<<<dim3(DFF/64, 64, NEXP), 256, 0, stream>>>(
      hn, w1, b1, cnt, offp, slot_tok, H1);
  moe_gemm2<<<dim3(DMODEL/64, 64, NEXP), 256, 0, stream>>>(
      H1, w2, b2, cnt, offp, slot_tok, slot_w, hres);

  final_kernel<<<NTOK*DMODEL/256, 256, 0, stream>>>(hres, out_h);
}

// Round 4
// 1056.432 us; speedup vs baseline: 1.7177x; 1.0324x over previous
//
#include <hip/hip_runtime.h>
#include <hip/hip_bf16.h>
#include <math.h>

#define NTOK   4096   // B*T
#define TSEQ   2048
#define DMODEL 1024
#define DINNER 2048
#define NSTATE 16
#define DTRANK 64
#define NEXP   8
#define DFF    2048
#define NCHUNK 32
#define CLEN   64     // TSEQ / NCHUNK

typedef __attribute__((ext_vector_type(8))) short short8;
typedef __attribute__((ext_vector_type(4))) float f32x4;

__device__ __forceinline__ float fast_rcp(float x){ return __builtin_amdgcn_rcpf(x); }
__device__ __forceinline__ float siluf(float x){ return x * fast_rcp(1.f + __expf(-x)); }

// fp32 -> bf16 (round-to-nearest-even), as raw ushort
__device__ __forceinline__ unsigned short f2bf(float x){
  unsigned int u = __float_as_uint(x);
  unsigned int r = (u + 0x7FFFu + ((u >> 16) & 1u)) >> 16;
  return (unsigned short)r;
}

// split fp32 -> (hi, lo) bf16 pair: x ~= hi + lo, |err| <= 2^-18 |x|
__device__ __forceinline__ void split4(float4 a, unsigned short* hi, unsigned short* lo){
  float av[4] = {a.x, a.y, a.z, a.w};
  #pragma unroll
  for (int j=0;j<4;j++){
    unsigned short hu = f2bf(av[j]);
    float hf = __uint_as_float((unsigned int)hu << 16);
    hi[j] = hu;
    lo[j] = f2bf(av[j] - hf);
  }
}

// ---------------------------------------------------------------------------
__global__ void zero_kernel(int* __restrict__ p){ p[threadIdx.x] = 0; }

// ---------------------------------------------------------------------------
// Pre-split fp32 array into hi/lo bf16 arrays. n multiple of 1024.
// ---------------------------------------------------------------------------
__global__ __launch_bounds__(256) void split_kernel(
    const float* __restrict__ in, unsigned short* __restrict__ hi,
    unsigned short* __restrict__ lo, int n)
{
  int i = (blockIdx.x*256 + threadIdx.x)*4;
  if (i >= n) return;
  float4 v = *(const float4*)(in + i);
  unsigned short ht[4], lt[4];
  split4(v, ht, lt);
  uint2 hw, lw;
  hw.x = (unsigned)ht[0] | ((unsigned)ht[1]<<16);
  hw.y = (unsigned)ht[2] | ((unsigned)ht[3]<<16);
  lw.x = (unsigned)lt[0] | ((unsigned)lt[1]<<16);
  lw.y = (unsigned)lt[2] | ((unsigned)lt[3]<<16);
  *(uint2*)(hi+i) = hw;
  *(uint2*)(lo+i) = lw;
}

// fp32 -> bf16 convert (no split). n multiple of 2048.
__global__ __launch_bounds__(256) void cvt_bf_kernel(
    const float* __restrict__ in, unsigned short* __restrict__ out, int n)
{
  int i = (blockIdx.x*256 + threadIdx.x)*8;
  if (i >= n) return;
  float4 a = *(const float4*)(in+i);
  float4 b = *(const float4*)(in+i+4);
  short8 v;
  v[0]=(short)f2bf(a.x); v[1]=(short)f2bf(a.y); v[2]=(short)f2bf(a.z); v[3]=(short)f2bf(a.w);
  v[4]=(short)f2bf(b.x); v[5]=(short)f2bf(b.y); v[6]=(short)f2bf(b.z); v[7]=(short)f2bf(b.w);
  *(short8*)(out+i) = v;
}

// ---------------------------------------------------------------------------
// Split-bf16 MFMA GEMM: C[M,N] = A[M,K] @ W[N,K]^T (+epilogue), ~fp32 accuracy.
// W pre-split (Whi/Wlo). A either pre-split (PS=true) or fp32 (split in-kernel).
// Per product: ah*bh + al*bh + ah*bl (fp32 acc).
// Tile BM x 128, BK=32, 256 threads / 4 waves; wave tile (16*RG) x 128.
// LDS row stride 40 shorts (80B, b128-aligned, ~2-way banks).
// EPI: 0 = +bias | 1 = plain | 2 = +bias,softplus | 3 = +resid
// ---------------------------------------------------------------------------
template<int EPI, int BM, bool PS>
__global__ __launch_bounds__(256) void gemm_big(
    const float* __restrict__ A,
    const unsigned short* __restrict__ Ahi, const unsigned short* __restrict__ Alo, int lda,
    const unsigned short* __restrict__ Whi, const unsigned short* __restrict__ Wlo, int ldw,
    int M, int N, int K,
    const float* __restrict__ bias,
    const float* __restrict__ resid, int ldr,
    float* __restrict__ out, int ldo)
{
  constexpr int RG  = BM/64;       // 16-row groups per wave (2 or 1)
  constexpr int TPR = 256/BM;      // threads per A row (2 or 4)
  constexpr int EA  = 32/TPR;      // A elems per thread per ktile (16 or 8)
  const int tid = threadIdx.x;
  const int m0 = blockIdx.y * BM;
  const int n0 = blockIdx.x * 128;

  __shared__ __align__(16) unsigned short Ahs[BM*40];
  __shared__ __align__(16) unsigned short Als[BM*40];
  __shared__ __align__(16) unsigned short Whs[128*40];
  __shared__ __align__(16) unsigned short Wls[128*40];

  const int arow = tid / TPR;
  const int aseg = (tid % TPR) * EA;
  const int wrow = tid >> 1;
  const int wseg = (tid & 1) * 16;

  const float* Ap = PS ? nullptr : (A + (size_t)(m0 + arow)*lda + aseg);
  const unsigned short* Aph = PS ? (Ahi + (size_t)(m0 + arow)*lda + aseg) : nullptr;
  const unsigned short* Apl = PS ? (Alo + (size_t)(m0 + arow)*lda + aseg) : nullptr;
  const bool wok = (n0 + wrow) < N;
  const unsigned short* Whp = Whi + (size_t)(n0 + wrow)*ldw + wseg;
  const unsigned short* Wlp = Wlo + (size_t)(n0 + wrow)*ldw + wseg;

  const int lane = tid & 63;
  const int wv   = tid >> 6;
  const int qd   = lane >> 4;
  const int mr   = lane & 15;

  f32x4 acc[RG][8];
  #pragma unroll
  for (int rg=0; rg<RG; rg++)
    #pragma unroll
    for (int ct=0; ct<8; ct++) acc[rg][ct] = (f32x4){0.f,0.f,0.f,0.f};

  const unsigned short* ardh = &Ahs[(wv*(16*RG) + mr)*40 + qd*8];
  const unsigned short* ardl = &Als[(wv*(16*RG) + mr)*40 + qd*8];
  const unsigned short* brdh = &Whs[mr*40 + qd*8];
  const unsigned short* brdl = &Wls[mr*40 + qd*8];

  const short8 z8 = {0,0,0,0,0,0,0,0};

  for (int kt = 0; kt < K; kt += 32){
    short8 ah[EA/8], al[EA/8];
    if (PS){
      #pragma unroll
      for (int h=0; h<EA/8; h++){
        ah[h] = *(const short8*)(Aph + kt + h*8);
        al[h] = *(const short8*)(Apl + kt + h*8);
      }
    } else {
      #pragma unroll
      for (int q=0; q<EA/4; q++){
        float4 f = *(const float4*)(Ap + kt + q*4);
        unsigned short ht[4], lt[4];
        split4(f, ht, lt);
        #pragma unroll
        for (int j=0;j<4;j++){
          ah[(q*4+j)/8][(q*4+j)&7] = (short)ht[j];
          al[(q*4+j)/8][(q*4+j)&7] = (short)lt[j];
        }
      }
    }
    short8 wh0 = wok ? *(const short8*)(Whp + kt)     : z8;
    short8 wh1 = wok ? *(const short8*)(Whp + kt + 8) : z8;
    short8 wl0 = wok ? *(const short8*)(Wlp + kt)     : z8;
    short8 wl1 = wok ? *(const short8*)(Wlp + kt + 8) : z8;
    __syncthreads();
    #pragma unroll
    for (int h=0; h<EA/8; h++){
      *(short8*)&Ahs[arow*40 + aseg + h*8] = ah[h];
      *(short8*)&Als[arow*40 + aseg + h*8] = al[h];
    }
    *(short8*)&Whs[wrow*40 + wseg]     = wh0;
    *(short8*)&Whs[wrow*40 + wseg + 8] = wh1;
    *(short8*)&Wls[wrow*40 + wseg]     = wl0;
    *(short8*)&Wls[wrow*40 + wseg + 8] = wl1;
    __syncthreads();
    #pragma unroll
    for (int rg=0; rg<RG; rg++){
      short8 af = *(const short8*)(ardh + rg*16*40);
      short8 alf= *(const short8*)(ardl + rg*16*40);
      #pragma unroll
      for (int ct=0; ct<8; ct++){
        short8 bh = *(const short8*)(brdh + ct*16*40);
        short8 bl = *(const short8*)(brdl + ct*16*40);
        f32x4 t = acc[rg][ct];
        t = __builtin_amdgcn_mfma_f32_16x16x32_bf16(af, bh, t, 0,0,0);
        t = __builtin_amdgcn_mfma_f32_16x16x32_bf16(alf, bh, t, 0,0,0);
        t = __builtin_amdgcn_mfma_f32_16x16x32_bf16(af, bl, t, 0,0,0);
        acc[rg][ct] = t;
      }
    }
  }

  #pragma unroll
  for (int rg=0; rg<RG; rg++){
    #pragma unroll
    for (int ct=0; ct<8; ct++){
      int colg = n0 + ct*16 + mr;
      if (colg >= N) continue;
      float bias_v = (EPI==0 || EPI==2) ? bias[colg] : 0.f;
      #pragma unroll
      for (int r=0;r<4;r++){
        int rowg = m0 + wv*(16*RG) + rg*16 + qd*4 + r;
        float v = acc[rg][ct][r];
        if (EPI == 0){ v += bias_v; }
        else if (EPI == 2){ v += bias_v; v = (v > 20.f) ? v : log1pf(expf(v)); }
        else if (EPI == 3){ v += resid[(size_t)rowg*ldr + colg]; }
        out[(size_t)rowg*ldo + colg] = v;
      }
    }
  }
}

// ---------------------------------------------------------------------------
// LayerNorm over D=1024 -> pre-split hi/lo bf16 (mamba branch; sole consumer
// is the in_proj GEMM, so fp32 output is skipped entirely).
// ---------------------------------------------------------------------------
__global__ __launch_bounds__(256) void ln_split_kernel(
    const float* __restrict__ x, const float* __restrict__ g, const float* __restrict__ b,
    unsigned short* __restrict__ hi, unsigned short* __restrict__ lo)
{
  int tok = blockIdx.x;
  int tid = threadIdx.x;
  const float* row = x + (size_t)tok * DMODEL;
  float v[4];
  float s = 0.f, sq = 0.f;
  #pragma unroll
  for (int j=0;j<4;j++){
    v[j] = row[j*256 + tid];
    s += v[j]; sq += v[j]*v[j];
  }
  #pragma unroll
  for (int o=1;o<64;o<<=1){ s += __shfl_xor(s,o,64); sq += __shfl_xor(sq,o,64); }
  __shared__ float ss[4], ssq[4];
  int wid = tid >> 6, lane = tid & 63;
  if (lane == 0){ ss[wid]=s; ssq[wid]=sq; }
  __syncthreads();
  s  = ss[0]+ss[1]+ss[2]+ss[3];
  sq = ssq[0]+ssq[1]+ssq[2]+ssq[3];
  float mu = s * (1.f/DMODEL);
  float var = sq * (1.f/DMODEL) - mu*mu;
  float rs = rsqrtf(var + 1e-5f);
  #pragma unroll
  for (int j=0;j<4;j++){
    int d = j*256 + tid;
    float o = (v[j]-mu)*rs*g[d] + b[d];
    unsigned short hu = f2bf(o);
    float hf = __uint_as_float((unsigned int)hu << 16);
    hi[(size_t)tok*DMODEL + d] = hu;
    lo[(size_t)tok*DMODEL + d] = f2bf(o - hf);
  }
}

// ---------------------------------------------------------------------------
// LayerNorm over D=1024 -> fp32 (router) + bf16 (moe_gemm1 A)
// ---------------------------------------------------------------------------
__global__ __launch_bounds__(256) void ln2_kernel(
    const float* __restrict__ x, const float* __restrict__ g, const float* __restrict__ b,
    float* __restrict__ out, unsigned short* __restrict__ outb)
{
  int tok = blockIdx.x;
  int tid = threadIdx.x;
  const float* row = x + (size_t)tok * DMODEL;
  float v[4];
  float s = 0.f, sq = 0.f;
  #pragma unroll
  for (int j=0;j<4;j++){
    v[j] = row[j*256 + tid];
    s += v[j]; sq += v[j]*v[j];
  }
  #pragma unroll
  for (int o=1;o<64;o<<=1){ s += __shfl_xor(s,o,64); sq += __shfl_xor(sq,o,64); }
  __shared__ float ss[4], ssq[4];
  int wid = tid >> 6, lane = tid & 63;
  if (lane == 0){ ss[wid]=s; ssq[wid]=sq; }
  __syncthreads();
  s  = ss[0]+ss[1]+ss[2]+ss[3];
  sq = ssq[0]+ssq[1]+ssq[2]+ssq[3];
  float mu = s * (1.f/DMODEL);
  float var = sq * (1.f/DMODEL) - mu*mu;
  float rs = rsqrtf(var + 1e-5f);
  #pragma unroll
  for (int j=0;j<4;j++){
    int d = j*256 + tid;
    float o = (v[j]-mu)*rs*g[d] + b[d];
    out[(size_t)tok*DMODEL + d] = o;
    outb[(size_t)tok*DMODEL + d] = f2bf(o);
  }
}

// ---------------------------------------------------------------------------
// Causal depthwise conv (KC=4) + SiLU.  xi = xz[:, 0:2048] (row stride 4096)
// ---------------------------------------------------------------------------
__global__ __launch_bounds__(256) void conv_kernel(
    const float* __restrict__ xz, const float* __restrict__ cw,
    const float* __restrict__ cb, float* __restrict__ xc)
{
  int i = blockIdx.x*256 + threadIdx.x;
  int tok = i >> 11;
  int ch  = i & 2047;
  int t   = tok & (TSEQ-1);
  int b   = tok >> 11;
  float acc = cb[ch];
  #pragma unroll
  for (int k=0;k<4;k++){
    int tt = t + k - 3;
    if (tt >= 0)
      acc = fmaf(cw[ch*4 + k], xz[(size_t)((b<<11)+tt)*4096 + ch], acc);
  }
  xc[i] = siluf(acc);
}

// ---------------------------------------------------------------------------
// Chunked parallel selective scan, lane-per-channel (verified round 2).
// ---------------------------------------------------------------------------
__global__ __launch_bounds__(256) void scan_partial(
    const float* __restrict__ xz, const float* __restrict__ xc,
    const float* __restrict__ proj, const float* __restrict__ A_log,
    float* __restrict__ P, float* __restrict__ Q)
{
  int tid = threadIdx.x;
  int ch  = blockIdx.x*256 + tid;
  int c   = blockIdx.y;
  int b   = blockIdx.z;
  float A[16];
  #pragma unroll
  for (int n=0;n<16;n++) A[n] = -expf(A_log[ch*NSTATE + n]);
  float h[16];
  #pragma unroll
  for (int n=0;n<16;n++) h[n] = 0.f;
  float sdt = 0.f;
  int tok0 = (b<<11) + c*CLEN;
  float dtv = xz[(size_t)tok0*4096 + ch];
  float xt  = xc[(size_t)tok0*2048 + ch];
  for (int i=0;i<CLEN;i++){
    int tn = tok0 + ((i+1 < CLEN) ? i+1 : i);
    float dtv_n = xz[(size_t)tn*4096 + ch];
    float xt_n  = xc[(size_t)tn*2048 + ch];
    const float4* pB = (const float4*)(proj + (size_t)(tok0+i)*96 + 64);
    float Bv[16];
    *(float4*)&Bv[0]  = pB[0];
    *(float4*)&Bv[4]  = pB[1];
    *(float4*)&Bv[8]  = pB[2];
    *(float4*)&Bv[12] = pB[3];
    float dxt = dtv*xt;
    sdt += dtv;
    #pragma unroll
    for (int n=0;n<16;n++){
      float dA = __expf(dtv*A[n]);
      h[n] = fmaf(dA, h[n], dxt*Bv[n]);
    }
    dtv = dtv_n; xt = xt_n;
  }
  size_t base = ((((size_t)(b*NCHUNK + c))<<11 | ch)<<4);
  #pragma unroll
  for (int n=0;n<16;n++){
    P[base+n] = __expf(A[n]*sdt);
    Q[base+n] = h[n];
  }
}

__global__ __launch_bounds__(256) void scan_combine(
    const float* __restrict__ Q, float* PH)
{
  int g = blockIdx.x*256 + threadIdx.x;
  int n = g & 15, ch = (g>>4) & 2047, b = g>>15;
  float hs = 0.f;
  for (int c=0;c<NCHUNK;c++){
    size_t idx = ((((size_t)(b*NCHUNK + c))<<11 | ch)<<4) | n;
    float pv = PH[idx];
    float qv = Q[idx];
    PH[idx] = hs;
    hs = fmaf(pv, hs, qv);
  }
}

__global__ __launch_bounds__(256) void scan_final(
    const float* __restrict__ xz, float* __restrict__ xc,
    const float* __restrict__ proj, const float* __restrict__ A_log,
    const float* __restrict__ Dskip, const float* __restrict__ Hs)
{
  int tid = threadIdx.x;
  int ch  = blockIdx.x*256 + tid;
  int c   = blockIdx.y;
  int b   = blockIdx.z;
  float A[16];
  #pragma unroll
  for (int n=0;n<16;n++) A[n] = -expf(A_log[ch*NSTATE + n]);
  float Dv = Dskip[ch];
  size_t base = ((((size_t)(b*NCHUNK + c))<<11 | ch)<<4);
  float h[16];
  #pragma unroll
  for (int n=0;n<16;n++) h[n] = Hs[base+n];
  int tok0 = (b<<11) + c*CLEN;
  float dtv = xz[(size_t)tok0*4096 + ch];
  float xt  = xc[(size_t)tok0*2048 + ch];
  float zv  = xz[(size_t)tok0*4096 + 2048 + ch];
  for (int i=0;i<CLEN;i++){
    int tn = tok0 + ((i+1 < CLEN) ? i+1 : i);
    float dtv_n = xz[(size_t)tn*4096 + ch];
    float xt_n  = xc[(size_t)tn*2048 + ch];
    float zv_n  = xz[(size_t)tn*4096 + 2048 + ch];
    const float4* pB = (const float4*)(proj + (size_t)(tok0+i)*96 + 64);
    float Bv[16], Cv[16];
    *(float4*)&Bv[0]  = pB[0];
    *(float4*)&Bv[4]  = pB[1];
    *(float4*)&Bv[8]  = pB[2];
    *(float4*)&Bv[12] = pB[3];
    *(float4*)&Cv[0]  = pB[4];
    *(float4*)&Cv[4]  = pB[5];
    *(float4*)&Cv[8]  = pB[6];
    *(float4*)&Cv[12] = pB[7];
    float dxt = dtv*xt;
    float y = xt*Dv;
    #pragma unroll
    for (int n=0;n<16;n++){
      float dA = __expf(dtv*A[n]);
      h[n] = fmaf(dA, h[n], dxt*Bv[n]);
      y = fmaf(h[n], Cv[n], y);
    }
    xc[(size_t)(tok0+i)*2048 + ch] = y * siluf(zv);
    dtv = dtv_n; xt = xt_n; zv = zv_n;
  }
}

// ---------------------------------------------------------------------------
// Router (kept precise: top-k decisions are tie-sensitive)
// ---------------------------------------------------------------------------
__global__ __launch_bounds__(256) void router_kernel(
    const float* __restrict__ hmoe, const float* __restrict__ rw,
    float* __restrict__ probs_out, int* __restrict__ cnt,
    int* __restrict__ tok_e0, int* __restrict__ tok_e1,
    float* __restrict__ tok_w0, float* __restrict__ tok_w1)
{
  int tok = blockIdx.x;
  int tid = threadIdx.x;
  int e = tid >> 5, l = tid & 31;
  float s = 0.f;
  const float* row = hmoe + (size_t)tok*DMODEL;
  const float* wr  = rw + (size_t)e*DMODEL;
  for (int d=l; d<DMODEL; d+=32) s = fmaf(row[d], wr[d], s);
  #pragma unroll
  for (int o=1;o<32;o<<=1) s += __shfl_xor(s,o,64);
  __shared__ float lg[8];
  if (l==0) lg[e]=s;
  __syncthreads();
  if (tid==0){
    float mx = lg[0];
    for (int k=1;k<8;k++) mx = fmaxf(mx, lg[k]);
    float pe[8]; float den=0.f;
    for (int k=0;k<8;k++){ pe[k]=expf(lg[k]-mx); den+=pe[k]; }
    float inv = 1.f/den;
    for (int k=0;k<8;k++) probs_out[tok*8+k] = pe[k]*inv;
    int i0=0;
    for (int k=1;k<8;k++) if (pe[k] > pe[i0]) i0=k;
    int i1 = (i0==0)?1:0;
    for (int k=0;k<8;k++) if (k!=i0 && pe[k] > pe[i1]) i1=k;
    float v0=pe[i0], v1=pe[i1], sw=v0+v1;
    tok_e0[tok]=i0; tok_e1[tok]=i1;
    tok_w0[tok]=v0/sw; tok_w1[tok]=v1/sw;
    atomicAdd(&cnt[i0],1); atomicAdd(&cnt[i1],1);
  }
}

__global__ void prefix_kernel(const int* cnt, int* off, int* fill){
  if (threadIdx.x==0){
    int s=0;
    for (int e=0;e<NEXP;e++){ off[e]=s; s+=cnt[e]; fill[e]=0; }
  }
}

__global__ __launch_bounds__(256) void fill_kernel(
    const int* tok_e0, const int* tok_e1, const float* tok_w0, const float* tok_w1,
    const int* off, int* fill, int* slot_tok, float* slot_w)
{
  int tok = blockIdx.x*256 + threadIdx.x;
  int e0=tok_e0[tok], e1=tok_e1[tok];
  int p0 = atomicAdd(&fill[e0],1); int s0 = off[e0]+p0;
  slot_tok[s0]=tok; slot_w[s0]=tok_w0[tok];
  int p1 = atomicAdd(&fill[e1],1); int s1 = off[e1]+p1;
  slot_tok[s1]=tok; slot_w[s1]=tok_w1[tok];
}

// ---------------------------------------------------------------------------
// MoE GEMM1 bf16 MFMA, BM=128 slots x BN=128: H1 = silu(hn_bf @ w1_bf^T + b1)
// All-bf16 inputs (pre-converted). RG=2, CT=8 -> 1.6 MFMA per ds_read_b128.
// ---------------------------------------------------------------------------
__global__ __launch_bounds__(256) void moe_gemm1(
    const unsigned short* __restrict__ hnb, const unsigned short* __restrict__ w1b,
    const float* __restrict__ b1,
    const int* __restrict__ cnt, const int* __restrict__ off,
    const int* __restrict__ slot_tok, unsigned short* __restrict__ H1)
{
  int e = blockIdx.z;
  int c = cnt[e];
  int r0 = blockIdx.y*128;
  if (r0 >= c) return;
  int base = off[e];
  int tid = threadIdx.x;
  __shared__ int toks[128];
  if (tid < 128) toks[tid] = (r0 + tid < c) ? slot_tok[base + r0 + tid] : -1;
  __shared__ __align__(16) unsigned short As[128*40];
  __shared__ __align__(16) unsigned short Ws[128*40];
  __syncthreads();

  const int n0   = blockIdx.x*128;
  const int srow = tid >> 1;
  const int sseg = (tid & 1) * 16;
  const int tok  = toks[srow];
  const bool aok = (tok >= 0);
  const unsigned short* Ap = hnb + (size_t)(aok ? tok : 0)*DMODEL + sseg;
  const unsigned short* Wp = w1b + (size_t)e*DFF*DMODEL + (size_t)(n0+srow)*DMODEL + sseg;

  const int lane = tid & 63;
  const int wv   = tid >> 6;
  const int qd   = lane >> 4;
  const int mr   = lane & 15;

  f32x4 acc[2][8];
  #pragma unroll
  for (int rg=0; rg<2; rg++)
    #pragma unroll
    for (int ct=0; ct<8; ct++) acc[rg][ct] = (f32x4){0.f,0.f,0.f,0.f};

  const unsigned short* ard = &As[(wv*32 + mr)*40 + qd*8];
  const unsigned short* brd = &Ws[mr*40 + qd*8];
  const short8 z8 = {0,0,0,0,0,0,0,0};

  for (int kt = 0; kt < DMODEL; kt += 32){
    short8 a0 = aok ? *(const short8*)(Ap + kt)     : z8;
    short8 a1 = aok ? *(const short8*)(Ap + kt + 8) : z8;
    short8 w0 = *(const short8*)(Wp + kt);
    short8 w1v= *(const short8*)(Wp + kt + 8);
    __syncthreads();
    *(short8*)&As[srow*40 + sseg]     = a0;
    *(short8*)&As[srow*40 + sseg + 8] = a1;
    *(short8*)&Ws[srow*40 + sseg]     = w0;
    *(short8*)&Ws[srow*40 + sseg + 8] = w1v;
    __syncthreads();
    #pragma unroll
    for (int rg=0; rg<2; rg++){
      short8 af = *(const short8*)(ard + rg*16*40);
      #pragma unroll
      for (int ct=0; ct<8; ct++){
        short8 bf = *(const short8*)(brd + ct*16*40);
        acc[rg][ct] = __builtin_amdgcn_mfma_f32_16x16x32_bf16(af, bf, acc[rg][ct], 0,0,0);
      }
    }
  }

  #pragma unroll
  for (int rg=0; rg<2; rg++){
    #pragma unroll
    for (int ct=0; ct<8; ct++){
      int colg = n0 + ct*16 + mr;
      float bias = b1[(size_t)e*DFF + colg];
      #pragma unroll
      for (int r=0;r<4;r++){
        int sl = wv*32 + rg*16 + qd*4 + r;
        if (toks[sl] < 0) continue;
        float v = acc[rg][ct][r] + bias;
        H1[(size_t)(base + r0 + sl)*DFF + colg] = f2bf(siluf(v));
      }
    }
  }
}

// ---------------------------------------------------------------------------
// MoE GEMM2 bf16 MFMA, BM=128 x BN=128: hres += w_slot*(H1 @ w2_bf^T + b2)
// ---------------------------------------------------------------------------
__global__ __launch_bounds__(256) void moe_gemm2(
    const unsigned short* __restrict__ H1, const unsigned short* __restrict__ w2b,
    const float* __restrict__ b2,
    const int* __restrict__ cnt, const int* __restrict__ off,
    const int* __restrict__ slot_tok, const float* __restrict__ slot_w,
    float* __restrict__ hres)
{
  int e = blockIdx.z;
  int c = cnt[e];
  int r0 = blockIdx.y*128;
  if (r0 >= c) return;
  int base = off[e];
  int tid = threadIdx.x;
  __shared__ int toks[128];
  __shared__ float wts[128];
  if (tid < 128){
    int r = r0 + tid;
    toks[tid] = (r<c) ? slot_tok[base+r] : -1;
    wts[tid]  = (r<c) ? slot_w[base+r] : 0.f;
  }
  __shared__ __align__(16) unsigned short As[128*40];
  __shared__ __align__(16) unsigned short Ws[128*40];
  __syncthreads();

  const int n0   = blockIdx.x*128;
  const int srow = tid >> 1;
  const int sseg = (tid & 1) * 16;
  const bool aok = (toks[srow] >= 0);
  const unsigned short* Ap = H1 + (size_t)(base + r0 + (aok ? srow : 0))*DFF + sseg;
  const unsigned short* Wp = w2b + (size_t)e*DMODEL*DFF + (size_t)(n0+srow)*DFF + sseg;

  const int lane = tid & 63;
  const int wv   = tid >> 6;
  const int qd   = lane >> 4;
  const int mr   = lane & 15;

  f32x4 acc[2][8];
  #pragma unroll
  for (int rg=0; rg<2; rg++)
    #pragma unroll
    for (int ct=0; ct<8; ct++) acc[rg][ct] = (f32x4){0.f,0.f,0.f,0.f};

  const unsigned short* ard = &As[(wv*32 + mr)*40 + qd*8];
  const unsigned short* brd = &Ws[mr*40 + qd*8];
  const short8 z8 = {0,0,0,0,0,0,0,0};

  for (int kt = 0; kt < DFF; kt += 32){
    short8 a0 = aok ? *(const short8*)(Ap + kt)     : z8;
    short8 a1 = aok ? *(const short8*)(Ap + kt + 8) : z8;
    short8 w0 = *(const short8*)(Wp + kt);
    short8 w1v= *(const short8*)(Wp + kt + 8);
    __syncthreads();
    *(short8*)&As[srow*40 + sseg]     = a0;
    *(short8*)&As[srow*40 + sseg + 8] = a1;
    *(short8*)&Ws[srow*40 + sseg]     = w0;
    *(short8*)&Ws[srow*40 + sseg + 8] = w1v;
    __syncthreads();
    #pragma unroll
    for (int rg=0; rg<2; rg++){
      short8 af = *(const short8*)(ard + rg*16*40);
      #pragma unroll
      for (int ct=0; ct<8; ct++){
        short8 bf = *(const short8*)(brd + ct*16*40);
        acc[rg][ct] = __builtin_amdgcn_mfma_f32_16x16x32_bf16(af, bf, acc[rg][ct], 0,0,0);
      }
    }
  }

  #pragma unroll
  for (int rg=0; rg<2; rg++){
    #pragma unroll
    for (int ct=0; ct<8; ct++){
      int colg = n0 + ct*16 + mr;
      float bias = b2[(size_t)e*DMODEL + colg];
      #pragma unroll
      for (int r=0;r<4;r++){
        int sl = wv*32 + rg*16 + qd*4 + r;
        int t = toks[sl];
        if (t < 0) continue;
        float v = acc[rg][ct][r] + bias;
        atomicAdd(&hres[(size_t)t*DMODEL + colg], wts[sl]*v);
      }
    }
  }
}

__global__ __launch_bounds__(256) void final_kernel(const float* __restrict__ hres,
                                                    float* __restrict__ out)
{
  int i = blockIdx.x*256 + threadIdx.x;
  out[i] = hres[i];
}

// ---------------------------------------------------------------------------
extern "C" void kernel_launch(void* const* d_in, const int* in_sizes, int n_in,
                              void* d_out, int out_size, void* d_ws, size_t ws_size,
                              hipStream_t stream)
{
  const float* x         = (const float*)d_in[0];
  const float* ln_m_g    = (const float*)d_in[1];
  const float* ln_m_b    = (const float*)d_in[2];
  const float* ln_e_g    = (const float*)d_in[3];
  const float* ln_e_b    = (const float*)d_in[4];
  const float* in_proj_w = (const float*)d_in[5];
  const float* in_proj_b = (const float*)d_in[6];
  const float* conv_w    = (const float*)d_in[7];
  const float* conv_b    = (const float*)d_in[8];
  const float* x_proj_w  = (const float*)d_in[9];
  const float* dt_proj_w = (const float*)d_in[10];
  const float* dt_proj_b = (const float*)d_in[11];
  const float* A_log     = (const float*)d_in[12];
  const float* D_skip    = (const float*)d_in[13];
  const float* out_proj_w= (const float*)d_in[14];
  const float* router_w  = (const float*)d_in[15];
  const float* w1        = (const float*)d_in[16];
  const float* b1        = (const float*)d_in[17];
  const float* w2        = (const float*)d_in[18];
  const float* b2        = (const float*)d_in[19];

  // Workspace map:
  //   [0,64M)    xz fp32 [4096,4096]; Wo overlay [32M,40M) after scan;
  //              after scan dead -> hres [0,16M), H1 bf16 [16M,48M),
  //              hn_bf [48M,56M)
  //   [64M,96M)  xc fp32; Wi hi/lo overlay before conv; w1_bf/w2_bf (32MB)
  //              during MoE (xc dead after out_proj; w2 cvt AFTER gemm1)
  //   [96M,97.5M) proj [4096,96]
  //   [97.5M,..) misc
  // d_out timeline: hn_hi/hn_lo (mamba LN) -> Wx/Wd splits -> P/Q (scans)
  //   -> hn fp32 (MoE LN) + probs -> final out.
  char* ws = (char*)d_ws;
  float* xz   = (float*)(ws + 0);
  float* xc   = (float*)(ws + 67108864ull);
  float* proj = (float*)(ws + 100663296ull);
  char*  misc = ws + 102236160ull;
  float* hres = (float*)(ws + 0);
  unsigned short* H1    = (unsigned short*)(ws + 16777216ull);
  unsigned short* hn_bf = (unsigned short*)(ws + 50331648ull);
  unsigned short* wmoe  = (unsigned short*)(ws + 67108864ull);  // w1_bf then w2_bf

  unsigned short* hn_hi = (unsigned short*)d_out;               // [0,8M)
  unsigned short* hn_lo = hn_hi + 4194304;                      // [8M,16M)
  float* hn   = (float*)d_out;
  float* Pbuf = (float*)d_out;                 // 2M floats (P -> Hs in-place)
  float* Qbuf = (float*)d_out + (2u<<20);      // 2M floats

  unsigned short* Wi_hi = (unsigned short*)(ws + 67108864ull);  // xc region pre-conv
  unsigned short* Wi_lo = Wi_hi + 4194304;
  unsigned short* Wo_hi = (unsigned short*)(ws + 33554432ull);  // xz mid, post-scan
  unsigned short* Wo_lo = Wo_hi + 2097152;
  unsigned short* Wx_hi = (unsigned short*)d_out;               // hn_hi/lo dead post in_proj
  unsigned short* Wx_lo = Wx_hi + 196608;
  unsigned short* Wd_hi = Wx_lo + 196608;
  unsigned short* Wd_lo = Wd_hi + 131072;

  int*   cnt      = (int*)(misc);
  int*   fill     = (int*)(misc + 64);
  int*   offp     = (int*)(misc + 128);
  int*   tok_e0   = (int*)(misc + 1024);
  int*   tok_e1   = (int*)(misc + 1024 + 16384);
  float* tok_w0   = (float*)(misc + 1024 + 32768);
  float* tok_w1   = (float*)(misc + 1024 + 49152);
  int*   slot_tok = (int*)(misc + 1024 + 65536);
  float* slot_w   = (float*)(misc + 1024 + 98304);
  float* out_h    = (float*)d_out;
  float* probs_out= (float*)d_out + 4194304;

  zero_kernel<<<1, 64, 0, stream>>>(cnt);

  // ---- Mamba branch ----
  split_kernel<<<4096, 256, 0, stream>>>(in_proj_w, Wi_hi, Wi_lo, 4194304);
  ln_split_kernel<<<NTOK, 256, 0, stream>>>(x, ln_m_g, ln_m_b, hn_hi, hn_lo);
  gemm_big<0,128,true><<<dim3(32, 32), 256, 0, stream>>>(
      nullptr, hn_hi, hn_lo, DMODEL, Wi_hi, Wi_lo, DMODEL, NTOK, 4096, DMODEL,
      in_proj_b, nullptr, 0, xz, 4096);
  split_kernel<<<192, 256, 0, stream>>>(x_proj_w, Wx_hi, Wx_lo, 196608);
  split_kernel<<<128, 256, 0, stream>>>(dt_proj_w, Wd_hi, Wd_lo, 131072);
  conv_kernel<<<NTOK*DINNER/256, 256, 0, stream>>>(xz, conv_w, conv_b, xc);
  gemm_big<1,64,false><<<dim3(1, 64), 256, 0, stream>>>(
      xc, nullptr, nullptr, DINNER, Wx_hi, Wx_lo, DINNER, NTOK, 96, DINNER,
      nullptr, nullptr, 0, proj, 96);
  gemm_big<2,128,false><<<dim3(16, 32), 256, 0, stream>>>(
      proj, nullptr, nullptr, 96, Wd_hi, Wd_lo, DTRANK, NTOK, DINNER, DTRANK,
      dt_proj_b, nullptr, 0, xz, 4096);
  scan_partial<<<dim3(DINNER/256, NCHUNK, 2), 256, 0, stream>>>(
      xz, xc, proj, A_log, Pbuf, Qbuf);
  scan_combine<<<256, 256, 0, stream>>>(Qbuf, Pbuf);
  scan_final<<<dim3(DINNER/256, NCHUNK, 2), 256, 0, stream>>>(
      xz, xc, proj, A_log, D_skip, Pbuf);
  split_kernel<<<2048, 256, 0, stream>>>(out_proj_w, Wo_hi, Wo_lo, 2097152);
  gemm_big<3,128,false><<<dim3(8, 32), 256, 0, stream>>>(
      xc, nullptr, nullptr, DINNER, Wo_hi, Wo_lo, DINNER, NTOK, DMODEL, DINNER,
      nullptr, x, DMODEL, hres, DMODEL);

  // ---- MoE branch ----
  ln2_kernel<<<NTOK, 256, 0, stream>>>(hres, ln_e_g, ln_e_b, hn, hn_bf);
  router_kernel<<<NTOK, 256, 0, stream>>>(hn, router_w, probs_out, cnt,
                                          tok_e0, tok_e1, tok_w0, tok_w1);
  prefix_kernel<<<1, 64, 0, stream>>>(cnt, offp, fill);
  fill_kernel<<<NTOK/256, 256, 0, stream>>>(tok_e0, tok_e1, tok_w0, tok_w1,
                                            offp, fill, slot_tok, slot_w);
  cvt_bf_kernel<<<8192, 256, 0, stream>>>(w1, wmoe, NEXP*DFF*DMODEL);
  moe_gemm1<<<dim3(DFF/128, 32, NEXP), 256, 0, stream>>>(
      hn_bf, wmoe, b1, cnt, offp, slot_tok, H1);
  cvt_bf_kernel<<<8192, 256, 0, stream>>>(w2, wmoe, NEXP*DMODEL*DFF);
  moe_gemm2<<<dim3(DMODEL/128, 32, NEXP), 256, 0, stream>>>(
      H1, wmoe, b2, cnt, offp, slot_tok, slot_w, hres);

  final_kernel<<<NTOK*DMODEL/256, 256, 0, stream>>>(hres, out_h);
}